// Round 10
// baseline (1710.328 us; speedup 1.0000x reference)
//
#include <hip/hip_runtime.h>
#include <hip/hip_bf16.h>

#define DEV __device__ __forceinline__

typedef __attribute__((ext_vector_type(4))) float f32x4;
typedef __attribute__((ext_vector_type(8))) short s16x8;
typedef unsigned short u16;

constexpr int Bsz = 8;      // batch
constexpr int S   = 2048;   // sequence
constexpr int Dm  = 512;    // model dim
constexpr int NHd = 8;      // heads
constexpr int FFd = 2048;
constexpr int Ln  = 4;
constexpr int T   = S * Bsz; // 16384 tokens; token index t = b*S + s (batch-major)

DEV u16 f2bf(float f) {
  union { float f; unsigned u; } v; v.f = f;
  unsigned r = v.u + 0x7fff + ((v.u >> 16) & 1);
  return (u16)(r >> 16);
}
DEV float bf2f(u16 a) { union { unsigned u; float f; } v; v.u = ((unsigned)a) << 16; return v.f; }
DEV float exp2g(float x) { return __builtin_amdgcn_exp2f(x); }   // v_exp_f32 (base-2 native)

typedef __attribute__((address_space(1))) const unsigned int guint;
typedef __attribute__((address_space(3))) unsigned int luint;
DEV void gload16(const void* g, void* l) {
  __builtin_amdgcn_global_load_lds((guint*)g, (luint*)l, 16, 0, 0);
}

// ---------------- weight fp32 -> bf16 ----------------
__global__ void cvt_bf16_kernel(const float* __restrict__ src, u16* __restrict__ dst, int n4) {
  int i = (blockIdx.x * 256 + threadIdx.x);
  if (i >= n4) return;
  float4 v = *reinterpret_cast<const float4*>(src + i * 4);
  ushort4 o; o.x = f2bf(v.x); o.y = f2bf(v.y); o.z = f2bf(v.z); o.w = f2bf(v.w);
  *reinterpret_cast<ushort4*>(dst + i * 4) = o;
}

// ---------------- Wo fuse: dst[l][n][k], k<512 from Wo_g, else Wo_l (K-concat) ----------------
__global__ void cvt_wo_kernel(const float* __restrict__ g, const float* __restrict__ l,
                              u16* __restrict__ dst) {
  int i = blockIdx.x * 256 + threadIdx.x;          // over 4-elem groups, total L*512*1024/4
  int e = i * 4;
  int li = e >> 19;
  int rem = e & 524287;
  int n = rem >> 10, k = rem & 1023;
  const float* src = (k < 512) ? (g + ((size_t)li * 512 + n) * 512 + k)
                               : (l + ((size_t)li * 512 + n) * 512 + (k - 512));
  float4 v = *reinterpret_cast<const float4*>(src);
  ushort4 o; o.x = f2bf(v.x); o.y = f2bf(v.y); o.z = f2bf(v.z); o.w = f2bf(v.w);
  *reinterpret_cast<ushort4*>(dst + e) = o;
}

// ---------------- embed + positional encoding (token t = b*S + s) ----------------
__global__ void embed_kernel(const float* __restrict__ x, const float* __restrict__ Wemb,
                             const float* __restrict__ bemb, float* __restrict__ hf,
                             u16* __restrict__ hb) {
  int t = blockIdx.x;
  int b = t >> 11, s = t & 2047;
  const float* xr = x + ((size_t)b * S + s) * 14;
  float xv[14];
  #pragma unroll
  for (int i = 0; i < 14; i++) xv[i] = xr[i];
  for (int d = threadIdx.x; d < Dm; d += blockDim.x) {
    const float* wr = Wemb + d * 14;
    float acc = bemb[d];
    #pragma unroll
    for (int i = 0; i < 14; i++) acc += xv[i] * wr[i];
    float ang = (float)s * expf((float)((d >> 1) * 2) * (-9.210340371976184f / 512.0f));
    acc += (d & 1) ? cosf(ang) : sinf(ang);
    hf[(size_t)t * Dm + d] = acc;
    hb[(size_t)t * Dm + d] = f2bf(acc);
  }
}

// ---------------- GEMM: C(M,N) = A(M,K) @ Bt(N,K)^T + bias ----------------
// OMODE: 1 = bf16 out, 2 = bf16 out + relu.
// VPACK (fused qkv GEMM, N=3072): 512-col sections {q_g,k_g,v_g,q_l,k_l,v_l};
//   v-sections scatter transposed into vpk[bh][d][s]; q/k write to qkv[t][2048];
//   bias1 = bqkv_g (cols<1536), bias2 = bqkv_l.
// BSUM: bias = bias1[col] + bias2[col] (fused wo GEMM).
template<int OMODE, int VPACK, int BSUM>
__global__ __launch_bounds__(256, 3)
void gemm_bt_kernel(const u16* __restrict__ A, const u16* __restrict__ Bt,
                    const float* __restrict__ bias1, const float* __restrict__ bias2,
                    void* __restrict__ Cout, u16* __restrict__ vpk,
                    int M, int N, int K) {
  __shared__ __align__(16) u16 As[2][128 * 32];
  __shared__ __align__(16) u16 Bs[2][128 * 32];
  const int tid = threadIdx.x;
  const int lane = tid & 63, w = tid >> 6;
  const int wr = w >> 1, wc = w & 1;
  const int lr = lane & 15, lg = lane >> 4;
  const int m0 = blockIdx.y * 128, n0 = blockIdx.x * 128;

  f32x4 acc[4][4] = {};

  const int c1 = tid, c2 = tid + 256;
  const u16* gA1 = A + (size_t)(m0 + (c1 >> 2)) * K + (c1 & 3) * 8;
  const u16* gA2 = A + (size_t)(m0 + (c2 >> 2)) * K + (c2 & 3) * 8;
  const u16* gB1 = Bt + (size_t)(n0 + (c1 >> 2)) * K + (c1 & 3) * 8;
  const u16* gB2 = Bt + (size_t)(n0 + (c2 >> 2)) * K + (c2 & 3) * 8;

  const int nk = K >> 5;
  auto stage = [&](int t, int c) {
    const int kt = t * 32;
    gload16(gA1 + kt, As[c] + c1 * 8); gload16(gA2 + kt, As[c] + c2 * 8);
    gload16(gB1 + kt, Bs[c] + c1 * 8); gload16(gB2 + kt, Bs[c] + c2 * 8);
  };

  stage(0, 0);
  for (int t = 0; t < nk; ++t) {
    const int c = t & 1;
    if (t + 1 < nk) {
      stage(t + 1, c ^ 1);
      asm volatile("s_waitcnt vmcnt(4)" ::: "memory");
    } else {
      asm volatile("s_waitcnt vmcnt(0)" ::: "memory");
    }
    __builtin_amdgcn_s_barrier();

    s16x8 a[4], bb[4];
    #pragma unroll
    for (int i = 0; i < 4; i++) {
      a[i]  = *reinterpret_cast<const s16x8*>(As[c] + ((wr * 64 + i * 16 + lr) * 32 + lg * 8));
      bb[i] = *reinterpret_cast<const s16x8*>(Bs[c] + ((wc * 64 + i * 16 + lr) * 32 + lg * 8));
    }
    #pragma unroll
    for (int mi = 0; mi < 4; mi++)
      #pragma unroll
      for (int ni = 0; ni < 4; ni++)
        acc[mi][ni] = __builtin_amdgcn_mfma_f32_16x16x32_bf16(a[mi], bb[ni], acc[mi][ni], 0, 0, 0);

    __builtin_amdgcn_s_barrier();
  }

  // epilogue
  const int sec = VPACK ? (n0 >> 9) : 0;            // block-uniform (128 | 512)
  const bool isv = VPACK && (sec == 2 || sec == 5);
  const int ldc = VPACK ? 2048 : N;
  const int csub = (VPACK && sec >= 3) ? 512 : 0;
  u16* vdst = nullptr;
  if (isv) vdst = vpk + (sec == 5 ? 8388608 : 0);

  #pragma unroll
  for (int mi = 0; mi < 4; mi++) {
    int row = m0 + wr * 64 + mi * 16 + lg * 4;
    #pragma unroll
    for (int ni = 0; ni < 4; ni++) {
      int col = n0 + wc * 64 + ni * 16 + lr;
      float bv;
      if (VPACK)      bv = (col < 1536) ? bias1[col] : bias2[col - 1536];
      else if (BSUM)  bv = bias1[col] + bias2[col];
      else            bv = bias1[col];
      if (isv) {
        int vcol = col - (sec == 2 ? 1024 : 2560);
        int hh = vcol >> 6, dd = vcol & 63;
        int bb2 = row >> 11, ss = row & 2047;       // rows = 4 consecutive s within one b
        ushort4 o;
        o.x = f2bf(acc[mi][ni][0] + bv);
        o.y = f2bf(acc[mi][ni][1] + bv);
        o.z = f2bf(acc[mi][ni][2] + bv);
        o.w = f2bf(acc[mi][ni][3] + bv);
        *reinterpret_cast<ushort4*>(vdst + ((size_t)(bb2 * NHd + hh) * 64 + dd) * S + ss) = o;
      } else {
        #pragma unroll
        for (int r = 0; r < 4; r++) {
          float v = acc[mi][ni][r] + bv;
          if (OMODE == 2) v = v > 0.f ? v : 0.f;
          ((u16*)Cout)[(size_t)(row + r) * ldc + (col - csub)] = f2bf(v);
        }
      }
    }
  }
}

// ---------------- flash attention v8: T14 reg-staged K/V, single LDS buffer, 4 blk/CU ----------
// Grid 2048: bid<1024 -> global (S_att=2048), else local (S_att=512). h = bid&7 (XCD pin).
// Per iter: issue flat global->reg loads for next tile (latency hides under compute);
// QK(A,B) -> softmax(max3 trees) -> P writes -> one lgkmcnt(0) -> PV(A,B) ->
// barrier (reads done) -> ds_write staged regs -> barrier (writes visible).
__global__ __launch_bounds__(256, 4)
void flash_kernel(const u16* __restrict__ qkv, const u16* __restrict__ vpk_all,
                  u16* __restrict__ ctx) {
  const int tid = threadIdx.x;
  const int lane = tid & 63, w = tid >> 6;
  const int lr = lane & 15, lg = lane >> 4;
  const int bid = blockIdx.x;
  const int half = bid >> 10;                 // 0 = global, 1 = local
  const int bid10 = bid & 1023;
  const int h = bid10 & 7;
  const int r_ = bid10 >> 3;
  const int S_att = half ? 512 : 2048;
  const int lognqb = half ? 2 : 4;
  const int qb = r_ & ((1 << lognqb) - 1);
  const int cw = r_ >> lognqb;
  const int b = cw & 7, n = cw >> 3;
  const int qoff = half ? 1024 : 0;
  const int koff = half ? 1536 : 512;
  const int coff = half ? 512 : 0;
  const u16* v_pk = vpk_all + (half ? 8388608 : 0);
  const int s_base = n * S_att;
  const int q0A = qb * 128 + w * 16;          // tile A rows
  const int q0B = q0A + 64;                   // tile B rows

  __shared__ __align__(16) u16 KT[4096];      // [key 0..63][dk 0..63], seg-swizzled (single buf)
  __shared__ __align__(16) u16 VT[4096];      // [d 0..63][k 0..63],    seg-swizzled (single buf)
  __shared__ __align__(16) u16 p_lds_all[4][2][16][72];
  u16 (*p_ldsA)[72] = p_lds_all[w][0];
  u16 (*p_ldsB)[72] = p_lds_all[w][1];

  const u16* vbase = v_pk + (size_t)(b * NHd + h) * 64 * S + s_base;

  // Q direct load + scale (0.125 * log2e) + repack to bf16, both tiles
  s16x8 qfA[2], qfB[2];
  {
    const float qs = 0.18033688011112042f;
    const u16* qpA = qkv + ((size_t)b * S + s_base + q0A + lr) * 2048 + qoff + h * 64 + lg * 8;
    const u16* qpB = qkv + ((size_t)b * S + s_base + q0B + lr) * 2048 + qoff + h * 64 + lg * 8;
    s16x8 a0 = *reinterpret_cast<const s16x8*>(qpA);
    s16x8 a1 = *reinterpret_cast<const s16x8*>(qpA + 32);
    s16x8 b0 = *reinterpret_cast<const s16x8*>(qpB);
    s16x8 b1 = *reinterpret_cast<const s16x8*>(qpB + 32);
    #pragma unroll
    for (int j = 0; j < 8; j++) {
      qfA[0][j] = (short)f2bf(bf2f((u16)a0[j]) * qs);
      qfA[1][j] = (short)f2bf(bf2f((u16)a1[j]) * qs);
      qfB[0][j] = (short)f2bf(bf2f((u16)b0[j]) * qs);
      qfB[1][j] = (short)f2bf(bf2f((u16)b1[j]) * qs);
    }
  }

  s16x8 ones;
  #pragma unroll
  for (int j = 0; j < 8; j++) ones[j] = (short)0x3F80;  // bf16 1.0

  float mA = -1e30f, mB = -1e30f;
  f32x4 laccA = (f32x4){0.f, 0.f, 0.f, 0.f}, laccB = (f32x4){0.f, 0.f, 0.f, 0.f};
  f32x4 oaccA[4], oaccB[4];
  #pragma unroll
  for (int nt = 0; nt < 4; nt++) {
    oaccA[nt] = (f32x4){0.f, 0.f, 0.f, 0.f};
    oaccB[nt] = (f32x4){0.f, 0.f, 0.f, 0.f};
  }

  // staging: thread t covers rows (t>>3) and (t>>3)+32, 16B segment (t&7),
  // global source pre-swizzled seg^=(row&7), LDS dest linear (rule #21).
  const int seg = tid & 7, sr1 = tid >> 3, sr2 = (tid >> 3) + 32;
  const int ssw1 = (seg ^ (sr1 & 7)) * 8, ssw2 = (seg ^ (sr2 & 7)) * 8;

  const u16* kroot = qkv + ((size_t)b * S + s_base) * 2048 + koff + h * 64;

  // T14 async-stage: global -> regs (issued early), ds_write after the read-barrier.
  s16x8 stg[4];
  auto load = [&](int kb) {
    const u16* kt = kroot + (size_t)kb * 2048;
    stg[0] = *reinterpret_cast<const s16x8*>(kt + (size_t)sr1 * 2048 + ssw1);
    stg[1] = *reinterpret_cast<const s16x8*>(kt + (size_t)sr2 * 2048 + ssw2);
    const u16* vt = vbase + kb;
    stg[2] = *reinterpret_cast<const s16x8*>(vt + (size_t)sr1 * S + ssw1);
    stg[3] = *reinterpret_cast<const s16x8*>(vt + (size_t)sr2 * S + ssw2);
  };
  auto commit = [&]() {
    *reinterpret_cast<s16x8*>(&KT[tid * 8]) = stg[0];
    *reinterpret_cast<s16x8*>(&KT[2048 + tid * 8]) = stg[1];
    *reinterpret_cast<s16x8*>(&VT[tid * 8]) = stg[2];
    *reinterpret_cast<s16x8*>(&VT[2048 + tid * 8]) = stg[3];
  };

  load(0);
  commit();
  __syncthreads();

  for (int kb = 0; kb < S_att; kb += 64) {
    const bool more = kb + 64 < S_att;
    if (more) load(kb + 64);   // flat loads -> regs; latency hides under QK/softmax/PV

    // K^T Q for both tiles (16 MFMA)
    f32x4 sgA[4], sgB[4];
    __builtin_amdgcn_s_setprio(1);
    #pragma unroll
    for (int g = 0; g < 4; g++) {
      const int key = g * 16 + lr, kw = key & 7;
      const u16* kp = &KT[key * 64];
      s16x8 k0 = *reinterpret_cast<const s16x8*>(kp + ((lg ^ kw) * 8));
      s16x8 k1 = *reinterpret_cast<const s16x8*>(kp + (((4 + lg) ^ kw) * 8));
      f32x4 sa = (f32x4){0.f, 0.f, 0.f, 0.f};
      sa = __builtin_amdgcn_mfma_f32_16x16x32_bf16(k0, qfA[0], sa, 0, 0, 0);
      sa = __builtin_amdgcn_mfma_f32_16x16x32_bf16(k1, qfA[1], sa, 0, 0, 0);
      sgA[g] = sa;
      f32x4 sb = (f32x4){0.f, 0.f, 0.f, 0.f};
      sb = __builtin_amdgcn_mfma_f32_16x16x32_bf16(k0, qfB[0], sb, 0, 0, 0);
      sb = __builtin_amdgcn_mfma_f32_16x16x32_bf16(k1, qfB[1], sb, 0, 0, 0);
      sgB[g] = sb;
    }
    __builtin_amdgcn_s_setprio(0);

    // tile maxes: max3-shaped chains (clang fuses fmaxf(fmaxf(a,b),c) -> v_max3_f32)
    float tmA, tmB;
    {
      float m_ = fmaxf(sgA[0][0], sgA[0][1]);
      m_ = fmaxf(fmaxf(m_, sgA[0][2]), sgA[0][3]);
      m_ = fmaxf(fmaxf(m_, sgA[1][0]), sgA[1][1]);
      m_ = fmaxf(fmaxf(m_, sgA[1][2]), sgA[1][3]);
      m_ = fmaxf(fmaxf(m_, sgA[2][0]), sgA[2][1]);
      m_ = fmaxf(fmaxf(m_, sgA[2][2]), sgA[2][3]);
      m_ = fmaxf(fmaxf(m_, sgA[3][0]), sgA[3][1]);
      m_ = fmaxf(fmaxf(m_, sgA[3][2]), sgA[3][3]);
      m_ = fmaxf(m_, __shfl_xor(m_, 16, 64));
      tmA = fmaxf(m_, __shfl_xor(m_, 32, 64));
      float u_ = fmaxf(sgB[0][0], sgB[0][1]);
      u_ = fmaxf(fmaxf(u_, sgB[0][2]), sgB[0][3]);
      u_ = fmaxf(fmaxf(u_, sgB[1][0]), sgB[1][1]);
      u_ = fmaxf(fmaxf(u_, sgB[1][2]), sgB[1][3]);
      u_ = fmaxf(fmaxf(u_, sgB[2][0]), sgB[2][1]);
      u_ = fmaxf(fmaxf(u_, sgB[2][2]), sgB[2][3]);
      u_ = fmaxf(fmaxf(u_, sgB[3][0]), sgB[3][1]);
      u_ = fmaxf(fmaxf(u_, sgB[3][2]), sgB[3][3]);
      u_ = fmaxf(u_, __shfl_xor(u_, 16, 64));
      tmB = fmaxf(u_, __shfl_xor(u_, 32, 64));
    }
    if (__any((int)(tmA > mA + 8.f))) {          // defer-max tile A
      float mnew = fmaxf(mA, tmA);
      float cf = exp2g(mA - mnew);
      mA = mnew;
      #pragma unroll
      for (int r = 0; r < 4; r++) {
        float co = __shfl(cf, lg * 4 + r, 16);
        laccA[r] *= co;
        #pragma unroll
        for (int nt = 0; nt < 4; nt++) oaccA[nt][r] *= co;
      }
    }
    if (__any((int)(tmB > mB + 8.f))) {          // defer-max tile B
      float mnew = fmaxf(mB, tmB);
      float cf = exp2g(mB - mnew);
      mB = mnew;
      #pragma unroll
      for (int r = 0; r < 4; r++) {
        float co = __shfl(cf, lg * 4 + r, 16);
        laccB[r] *= co;
        #pragma unroll
        for (int nt = 0; nt < 4; nt++) oaccB[nt][r] *= co;
      }
    }

    // exp + pack + write BOTH tiles (separate LDS regions), then one drain
    #pragma unroll
    for (int g = 0; g < 4; g++) {
      float e0 = exp2g(sgA[g][0] - mA);
      float e1 = exp2g(sgA[g][1] - mA);
      float e2 = exp2g(sgA[g][2] - mA);
      float e3 = exp2g(sgA[g][3] - mA);
      unsigned p01, p23;
      asm("v_cvt_pk_bf16_f32 %0, %1, %2" : "=v"(p01) : "v"(e0), "v"(e1));
      asm("v_cvt_pk_bf16_f32 %0, %1, %2" : "=v"(p23) : "v"(e2), "v"(e3));
      uint2 pk; pk.x = p01; pk.y = p23;
      *reinterpret_cast<uint2*>(&p_ldsA[lr][g * 16 + lg * 4]) = pk;
    }
    #pragma unroll
    for (int g = 0; g < 4; g++) {
      float e0 = exp2g(sgB[g][0] - mB);
      float e1 = exp2g(sgB[g][1] - mB);
      float e2 = exp2g(sgB[g][2] - mB);
      float e3 = exp2g(sgB[g][3] - mB);
      unsigned p01, p23;
      asm("v_cvt_pk_bf16_f32 %0, %1, %2" : "=v"(p01) : "v"(e0), "v"(e1));
      asm("v_cvt_pk_bf16_f32 %0, %1, %2" : "=v"(p23) : "v"(e2), "v"(e3));
      uint2 pk; pk.x = p01; pk.y = p23;
      *reinterpret_cast<uint2*>(&p_ldsB[lr][g * 16 + lg * 4]) = pk;
    }
    asm volatile("s_waitcnt lgkmcnt(0)" ::: "memory");  // RAW: all P writes visible

    // PV both tiles
    __builtin_amdgcn_s_setprio(1);
    #pragma unroll
    for (int kc = 0; kc < 2; kc++) {
      s16x8 paA = *reinterpret_cast<const s16x8*>(&p_ldsA[lr][kc * 32 + lg * 8]);
      s16x8 paB = *reinterpret_cast<const s16x8*>(&p_ldsB[lr][kc * 32 + lg * 8]);
      laccA = __builtin_amdgcn_mfma_f32_16x16x32_bf16(paA, ones, laccA, 0, 0, 0);
      laccB = __builtin_amdgcn_mfma_f32_16x16x32_bf16(paB, ones, laccB, 0, 0, 0);
      #pragma unroll
      for (int nt = 0; nt < 4; nt++) {
        const int d = nt * 16 + lr;
        s16x8 vfr = *reinterpret_cast<const s16x8*>(
            &VT[d * 64 + (((kc * 4 + lg) ^ (d & 7)) * 8)]);
        oaccA[nt] = __builtin_amdgcn_mfma_f32_16x16x32_bf16(paA, vfr, oaccA[nt], 0, 0, 0);
        oaccB[nt] = __builtin_amdgcn_mfma_f32_16x16x32_bf16(paB, vfr, oaccB[nt], 0, 0, 0);
      }
    }
    __builtin_amdgcn_s_setprio(0);

    __syncthreads();            // all waves done READING KT/VT/p_lds
    if (more) commit();         // overwrite KT/VT (compiler inserts vmcnt before reg use)
    __syncthreads();            // ds_writes visible before next iter's QK
  }

  #pragma unroll
  for (int nt = 0; nt < 4; nt++)
    #pragma unroll
    for (int r = 0; r < 4; r++) {
      float vA = oaccA[nt][r] / laccA[r];
      size_t tqA = (size_t)b * S + s_base + q0A + lg * 4 + r;
      ctx[tqA * 1024 + coff + h * 64 + nt * 16 + lr] = f2bf(vA);
      float vB = oaccB[nt][r] / laccB[r];
      size_t tqB = (size_t)b * S + s_base + q0B + lg * 4 + r;
      ctx[tqB * 1024 + coff + h * 64 + nt * 16 + lr] = f2bf(vB);
    }
}

// ---------------- residual add (bf16 branch) + LayerNorm ----------------
template<int NADD>
__global__ void ln_kernel(const float* __restrict__ hin, const u16* __restrict__ a1,
                          const u16* __restrict__ a2, const float* __restrict__ gamma,
                          const float* __restrict__ beta, float* __restrict__ hf,
                          u16* __restrict__ hb) {
  int row = blockIdx.x * 4 + (threadIdx.x >> 6);
  int lane = threadIdx.x & 63;
  size_t base = (size_t)row * 512 + lane * 8;
  float4 h0 = *reinterpret_cast<const float4*>(hin + base);
  float4 h1 = *reinterpret_cast<const float4*>(hin + base + 4);
  s16x8 x1 = *reinterpret_cast<const s16x8*>(a1 + base);
  s16x8 x2 = {};
  if (NADD == 2) x2 = *reinterpret_cast<const s16x8*>(a2 + base);
  float v[8];
  float hv[8] = {h0.x, h0.y, h0.z, h0.w, h1.x, h1.y, h1.z, h1.w};
  float sum = 0.f;
  #pragma unroll
  for (int j = 0; j < 8; j++) {
    float t = hv[j] + bf2f((u16)x1[j]);
    if (NADD == 2) t += bf2f((u16)x2[j]);
    v[j] = t; sum += t;
  }
  #pragma unroll
  for (int o = 32; o >= 1; o >>= 1) sum += __shfl_xor(sum, o, 64);
  float mean = sum * (1.0f / 512.0f);
  float sq = 0.f;
  #pragma unroll
  for (int j = 0; j < 8; j++) { float d = v[j] - mean; sq += d * d; }
  #pragma unroll
  for (int o = 32; o >= 1; o >>= 1) sq += __shfl_xor(sq, o, 64);
  float rstd = rsqrtf(sq * (1.0f / 512.0f) + 1e-5f);
  #pragma unroll
  for (int j = 0; j < 8; j++) {
    int d = lane * 8 + j;
    float o = (v[j] - mean) * rstd * gamma[d] + beta[d];
    hf[base + j] = o;
    hb[base + j] = f2bf(o);
  }
}

// ---------------- final projection (token (s=S-1, b) = b*S + S-1) ----------------
__global__ void out_kernel(const float* __restrict__ hf, const float* __restrict__ Wout,
                           const float* __restrict__ bout, float* __restrict__ out) {
  int b = blockIdx.x; int lane = threadIdx.x;
  size_t base = ((size_t)b * S + S - 1) * 512;
  float s = 0.f;
  #pragma unroll
  for (int j = 0; j < 8; j++) { int d = lane * 8 + j; s += hf[base + d] * Wout[d]; }
  #pragma unroll
  for (int o = 32; o >= 1; o >>= 1) s += __shfl_xor(s, o, 64);
  if (lane == 0) out[b] = s + bout[0];
}

extern "C" void kernel_launch(void* const* d_in, const int* in_sizes, int n_in,
                              void* d_out, int out_size, void* d_ws, size_t ws_size,
                              hipStream_t stream) {
  (void)in_sizes; (void)n_in; (void)out_size; (void)ws_size;
  const float* x      = (const float*)d_in[0];
  const float* W_emb  = (const float*)d_in[1];
  const float* b_emb  = (const float*)d_in[2];
  const float* Wqkv_g = (const float*)d_in[3];
  const float* bqkv_g = (const float*)d_in[4];
  const float* Wo_g   = (const float*)d_in[5];
  const float* bo_g   = (const float*)d_in[6];
  const float* Wqkv_l = (const float*)d_in[7];
  const float* bqkv_l = (const float*)d_in[8];
  const float* Wo_l   = (const float*)d_in[9];
  const float* bo_l   = (const float*)d_in[10];
  const float* W1     = (const float*)d_in[11];
  const float* b1f    = (const float*)d_in[12];
  const float* W2     = (const float*)d_in[13];
  const float* b2f    = (const float*)d_in[14];
  const float* g1     = (const float*)d_in[15];
  const float* be1    = (const float*)d_in[16];
  const float* g2     = (const float*)d_in[17];
  const float* be2    = (const float*)d_in[18];
  const float* W_out  = (const float*)d_in[19];
  const float* b_out  = (const float*)d_in[20];
  float* out = (float*)d_out;

  char* ws = (char*)d_ws;
  u16*   w_bf = (u16*)ws;                       // 32 MiB bf16 weights
  float* h_f  = (float*)(ws + 33554432);        // 32 MiB fp32 master
  u16*   h_b  = (u16*)(ws + 67108864);          // 16 MiB bf16 mirror
  u16*   qkv  = (u16*)(ws + 83886080);          // 64 MiB: [t][2048] = {q_g,k_g,q_l,k_l}
  u16*   ff1  = (u16*)(ws + 83886080);          // aliases qkv (dead by FFN)
  u16*   vpk  = (u16*)(ws + 150994944);         // 32 MiB: v_pk_g | v_pk_l (+8388608 elems)
  u16*   ctx  = (u16*)(ws + 184549376);         // 32 MiB: [t][1024] = ctx_g | ctx_l
  u16*   go   = (u16*)(ws + 218103808);         // 16 MiB bf16 (wo out, also ff2 out) -> 224 MiB

  // fused weight layouts
  u16* wqkvF = w_bf;                 // per layer [3072][512]: rows 0-1535 g, 1536-3071 l
  u16* woF   = w_bf + 6291456;       // per layer [512][1024]: k<512 g, k>=512 l
  u16* w1b   = w_bf + 8388608;
  u16* w2b   = w_bf + 12582912;

  auto cvt = [&](const float* s_, u16* d_, int n) {
    cvt_bf16_kernel<<<(n / 4 + 255) / 256, 256, 0, stream>>>(s_, d_, n / 4);
  };
  for (int i = 0; i < Ln; i++) {
    cvt(Wqkv_g + (size_t)i * 786432, wqkvF + (size_t)i * 1572864, 786432);
    cvt(Wqkv_l + (size_t)i * 786432, wqkvF + (size_t)i * 1572864 + 786432, 786432);
  }
  cvt_wo_kernel<<<2048, 256, 0, stream>>>(Wo_g, Wo_l, woF);
  cvt(W1, w1b, 4194304);
  cvt(W2, w2b, 4194304);

  embed_kernel<<<T, 256, 0, stream>>>(x, W_emb, b_emb, h_f, h_b);

  for (int i = 0; i < Ln; i++) {
    // fused qkv (global+local) with V-transpose epilogue
    gemm_bt_kernel<1, 1, 0><<<dim3(3072 / 128, T / 128), 256, 0, stream>>>(
        h_b, wqkvF + (size_t)i * 1572864, bqkv_g + i * 1536, bqkv_l + i * 1536,
        qkv, vpk, T, 3072, 512);
    // merged global+local attention (one launch, 2048 blocks)
    flash_kernel<<<dim3(2048), 256, 0, stream>>>(qkv, vpk, ctx);
    // fused output projection: [ctx_g|ctx_l] @ [Wo_g;Wo_l], bias = bo_g + bo_l
    gemm_bt_kernel<1, 0, 1><<<dim3(512 / 128, T / 128), 256, 0, stream>>>(
        ctx, woF + (size_t)i * 524288, bo_g + i * 512, bo_l + i * 512,
        go, nullptr, T, 512, 1024);
    // LN1
    ln_kernel<1><<<T / 4, 256, 0, stream>>>(h_f, go, nullptr, g1 + i * 512, be1 + i * 512, h_f, h_b);
    // FFN
    gemm_bt_kernel<2, 0, 0><<<dim3(FFd / 128, T / 128), 256, 0, stream>>>(
        h_b, w1b + (size_t)i * 1048576, b1f + i * 2048, nullptr, ff1, nullptr, T, 2048, 512);
    gemm_bt_kernel<1, 0, 0><<<dim3(512 / 128, T / 128), 256, 0, stream>>>(
        ff1, w2b + (size_t)i * 1048576, b2f + i * 512, nullptr, go, nullptr, T, 512, 2048);
    ln_kernel<1><<<T / 4, 256, 0, stream>>>(h_f, go, nullptr, g2 + i * 512, be2 + i * 512, h_f, h_b);
  }

  out_kernel<<<Bsz, 64, 0, stream>>>(h_f, W_out, b_out, out);
}

// Round 11
// 1510.205 us; speedup vs baseline: 1.1325x; 1.1325x over previous
//
#include <hip/hip_runtime.h>
#include <hip/hip_bf16.h>

#define DEV __device__ __forceinline__

typedef __attribute__((ext_vector_type(4))) float f32x4;
typedef __attribute__((ext_vector_type(8))) short s16x8;
typedef unsigned short u16;

constexpr int Bsz = 8;      // batch
constexpr int S   = 2048;   // sequence
constexpr int Dm  = 512;    // model dim
constexpr int NHd = 8;      // heads
constexpr int FFd = 2048;
constexpr int Ln  = 4;
constexpr int T   = S * Bsz; // 16384 tokens; token index t = b*S + s (batch-major)

DEV u16 f2bf(float f) {
  union { float f; unsigned u; } v; v.f = f;
  unsigned r = v.u + 0x7fff + ((v.u >> 16) & 1);
  return (u16)(r >> 16);
}
DEV float bf2f(u16 a) { union { unsigned u; float f; } v; v.u = ((unsigned)a) << 16; return v.f; }
DEV float exp2g(float x) { return __builtin_amdgcn_exp2f(x); }   // v_exp_f32 (base-2 native)

typedef __attribute__((address_space(1))) const unsigned int guint;
typedef __attribute__((address_space(3))) unsigned int luint;
DEV void gload16(const void* g, void* l) {
  __builtin_amdgcn_global_load_lds((guint*)g, (luint*)l, 16, 0, 0);
}

// ---------------- weight fp32 -> bf16 ----------------
__global__ void cvt_bf16_kernel(const float* __restrict__ src, u16* __restrict__ dst, int n4) {
  int i = (blockIdx.x * 256 + threadIdx.x);
  if (i >= n4) return;
  float4 v = *reinterpret_cast<const float4*>(src + i * 4);
  ushort4 o; o.x = f2bf(v.x); o.y = f2bf(v.y); o.z = f2bf(v.z); o.w = f2bf(v.w);
  *reinterpret_cast<ushort4*>(dst + i * 4) = o;
}

// ---------------- Wo fuse: dst[l][n][k], k<512 from Wo_g, else Wo_l (K-concat) ----------------
__global__ void cvt_wo_kernel(const float* __restrict__ g, const float* __restrict__ l,
                              u16* __restrict__ dst) {
  int i = blockIdx.x * 256 + threadIdx.x;          // over 4-elem groups, total L*512*1024/4
  int e = i * 4;
  int li = e >> 19;
  int rem = e & 524287;
  int n = rem >> 10, k = rem & 1023;
  const float* src = (k < 512) ? (g + ((size_t)li * 512 + n) * 512 + k)
                               : (l + ((size_t)li * 512 + n) * 512 + (k - 512));
  float4 v = *reinterpret_cast<const float4*>(src);
  ushort4 o; o.x = f2bf(v.x); o.y = f2bf(v.y); o.z = f2bf(v.z); o.w = f2bf(v.w);
  *reinterpret_cast<ushort4*>(dst + e) = o;
}

// ---------------- embed + positional encoding (token t = b*S + s) ----------------
__global__ void embed_kernel(const float* __restrict__ x, const float* __restrict__ Wemb,
                             const float* __restrict__ bemb, float* __restrict__ hf,
                             u16* __restrict__ hb) {
  int t = blockIdx.x;
  int b = t >> 11, s = t & 2047;
  const float* xr = x + ((size_t)b * S + s) * 14;
  float xv[14];
  #pragma unroll
  for (int i = 0; i < 14; i++) xv[i] = xr[i];
  for (int d = threadIdx.x; d < Dm; d += blockDim.x) {
    const float* wr = Wemb + d * 14;
    float acc = bemb[d];
    #pragma unroll
    for (int i = 0; i < 14; i++) acc += xv[i] * wr[i];
    float ang = (float)s * expf((float)((d >> 1) * 2) * (-9.210340371976184f / 512.0f));
    acc += (d & 1) ? cosf(ang) : sinf(ang);
    hf[(size_t)t * Dm + d] = acc;
    hb[(size_t)t * Dm + d] = f2bf(acc);
  }
}

// ---------------- GEMM: C(M,N) = A(M,K) @ Bt(N,K)^T + bias ----------------
// 1D grid + T1 XCD-chunked swizzle: consecutive logical row-panels stay on one XCD
// (A-panel fetched into 1 L2 instead of 8). nwg % 8 == 0 for all our shapes.
// OMODE: 1 = bf16 out, 2 = bf16 out + relu.
// VPACK (fused qkv GEMM, N=3072): v-sections scatter transposed into vpk; q/k -> qkv[t][2048].
// BSUM: bias = bias1[col] + bias2[col] (fused wo GEMM).
template<int OMODE, int VPACK, int BSUM>
__global__ __launch_bounds__(256, 3)
void gemm_bt_kernel(const u16* __restrict__ A, const u16* __restrict__ Bt,
                    const float* __restrict__ bias1, const float* __restrict__ bias2,
                    void* __restrict__ Cout, u16* __restrict__ vpk,
                    int M, int N, int K, int nx) {
  __shared__ __align__(16) u16 As[2][128 * 32];
  __shared__ __align__(16) u16 Bs[2][128 * 32];
  const int tid = threadIdx.x;
  const int lane = tid & 63, w = tid >> 6;
  const int wr = w >> 1, wc = w & 1;
  const int lr = lane & 15, lg = lane >> 4;

  // T1: bijective XCD-chunked remap (gridDim.x % 8 == 0)
  const int bid = blockIdx.x;
  const int chunk = gridDim.x >> 3;
  const int swz = (bid & 7) * chunk + (bid >> 3);
  const int n0 = (swz % nx) * 128, m0 = (swz / nx) * 128;

  f32x4 acc[4][4] = {};

  const int c1 = tid, c2 = tid + 256;
  const u16* gA1 = A + (size_t)(m0 + (c1 >> 2)) * K + (c1 & 3) * 8;
  const u16* gA2 = A + (size_t)(m0 + (c2 >> 2)) * K + (c2 & 3) * 8;
  const u16* gB1 = Bt + (size_t)(n0 + (c1 >> 2)) * K + (c1 & 3) * 8;
  const u16* gB2 = Bt + (size_t)(n0 + (c2 >> 2)) * K + (c2 & 3) * 8;

  const int nk = K >> 5;
  auto stage = [&](int t, int c) {
    const int kt = t * 32;
    gload16(gA1 + kt, As[c] + c1 * 8); gload16(gA2 + kt, As[c] + c2 * 8);
    gload16(gB1 + kt, Bs[c] + c1 * 8); gload16(gB2 + kt, Bs[c] + c2 * 8);
  };

  stage(0, 0);
  for (int t = 0; t < nk; ++t) {
    const int c = t & 1;
    if (t + 1 < nk) {
      stage(t + 1, c ^ 1);
      asm volatile("s_waitcnt vmcnt(4)" ::: "memory");
    } else {
      asm volatile("s_waitcnt vmcnt(0)" ::: "memory");
    }
    __builtin_amdgcn_s_barrier();

    s16x8 a[4], bb[4];
    #pragma unroll
    for (int i = 0; i < 4; i++) {
      a[i]  = *reinterpret_cast<const s16x8*>(As[c] + ((wr * 64 + i * 16 + lr) * 32 + lg * 8));
      bb[i] = *reinterpret_cast<const s16x8*>(Bs[c] + ((wc * 64 + i * 16 + lr) * 32 + lg * 8));
    }
    #pragma unroll
    for (int mi = 0; mi < 4; mi++)
      #pragma unroll
      for (int ni = 0; ni < 4; ni++)
        acc[mi][ni] = __builtin_amdgcn_mfma_f32_16x16x32_bf16(a[mi], bb[ni], acc[mi][ni], 0, 0, 0);

    __builtin_amdgcn_s_barrier();
  }

  // epilogue
  const int sec = VPACK ? (n0 >> 9) : 0;            // block-uniform (128 | 512)
  const bool isv = VPACK && (sec == 2 || sec == 5);
  const int ldc = VPACK ? 2048 : N;
  const int csub = (VPACK && sec >= 3) ? 512 : 0;
  u16* vdst = nullptr;
  if (isv) vdst = vpk + (sec == 5 ? 8388608 : 0);

  #pragma unroll
  for (int mi = 0; mi < 4; mi++) {
    int row = m0 + wr * 64 + mi * 16 + lg * 4;
    #pragma unroll
    for (int ni = 0; ni < 4; ni++) {
      int col = n0 + wc * 64 + ni * 16 + lr;
      float bv;
      if (VPACK)      bv = (col < 1536) ? bias1[col] : bias2[col - 1536];
      else if (BSUM)  bv = bias1[col] + bias2[col];
      else            bv = bias1[col];
      if (isv) {
        int vcol = col - (sec == 2 ? 1024 : 2560);
        int hh = vcol >> 6, dd = vcol & 63;
        int bb2 = row >> 11, ss = row & 2047;       // rows = 4 consecutive s within one b
        ushort4 o;
        o.x = f2bf(acc[mi][ni][0] + bv);
        o.y = f2bf(acc[mi][ni][1] + bv);
        o.z = f2bf(acc[mi][ni][2] + bv);
        o.w = f2bf(acc[mi][ni][3] + bv);
        *reinterpret_cast<ushort4*>(vdst + ((size_t)(bb2 * NHd + hh) * 64 + dd) * S + ss) = o;
      } else {
        #pragma unroll
        for (int r = 0; r < 4; r++) {
          float v = acc[mi][ni][r] + bv;
          if (OMODE == 2) v = v > 0.f ? v : 0.f;
          ((u16*)Cout)[(size_t)(row + r) * ldc + (col - csub)] = f2bf(v);
        }
      }
    }
  }
}

// ---------------- flash attention v9: R9 structure (dbuf gload_lds) + max3 trees ----------------
// Grid 2048: bid<1024 -> global (S_att=2048), else local (S_att=512). h = bid&7 (XCD pin).
// Per 64-k iter: prefetch next tile (gload_lds, dbuf) -> QK(A,B) -> softmax -> P writes
// -> ONE lgkmcnt(0) -> PV(A,B) -> __syncthreads (drains stage vmcnt + LDS reads).
__global__ __launch_bounds__(256, 3)
void flash_kernel(const u16* __restrict__ qkv, const u16* __restrict__ vpk_all,
                  u16* __restrict__ ctx) {
  const int tid = threadIdx.x;
  const int lane = tid & 63, w = tid >> 6;
  const int lr = lane & 15, lg = lane >> 4;
  const int bid = blockIdx.x;
  const int half = bid >> 10;                 // 0 = global, 1 = local
  const int bid10 = bid & 1023;
  const int h = bid10 & 7;
  const int r_ = bid10 >> 3;
  const int S_att = half ? 512 : 2048;
  const int lognqb = half ? 2 : 4;
  const int qb = r_ & ((1 << lognqb) - 1);
  const int cw = r_ >> lognqb;
  const int b = cw & 7, n = cw >> 3;
  const int qoff = half ? 1024 : 0;
  const int koff = half ? 1536 : 512;
  const int coff = half ? 512 : 0;
  const u16* v_pk = vpk_all + (half ? 8388608 : 0);
  const int s_base = n * S_att;
  const int q0A = qb * 128 + w * 16;          // tile A rows
  const int q0B = q0A + 64;                   // tile B rows

  __shared__ __align__(16) u16 KT[2][4096];   // [key 0..63][dk 0..63], seg-swizzled
  __shared__ __align__(16) u16 VT[2][4096];   // [d 0..63][k 0..63],    seg-swizzled
  __shared__ __align__(16) u16 p_lds_all[4][2][16][72];
  u16 (*p_ldsA)[72] = p_lds_all[w][0];
  u16 (*p_ldsB)[72] = p_lds_all[w][1];

  const u16* vbase = v_pk + (size_t)(b * NHd + h) * 64 * S + s_base;

  // Q direct load + scale (0.125 * log2e) + repack to bf16, both tiles
  s16x8 qfA[2], qfB[2];
  {
    const float qs = 0.18033688011112042f;
    const u16* qpA = qkv + ((size_t)b * S + s_base + q0A + lr) * 2048 + qoff + h * 64 + lg * 8;
    const u16* qpB = qkv + ((size_t)b * S + s_base + q0B + lr) * 2048 + qoff + h * 64 + lg * 8;
    s16x8 a0 = *reinterpret_cast<const s16x8*>(qpA);
    s16x8 a1 = *reinterpret_cast<const s16x8*>(qpA + 32);
    s16x8 b0 = *reinterpret_cast<const s16x8*>(qpB);
    s16x8 b1 = *reinterpret_cast<const s16x8*>(qpB + 32);
    #pragma unroll
    for (int j = 0; j < 8; j++) {
      qfA[0][j] = (short)f2bf(bf2f((u16)a0[j]) * qs);
      qfA[1][j] = (short)f2bf(bf2f((u16)a1[j]) * qs);
      qfB[0][j] = (short)f2bf(bf2f((u16)b0[j]) * qs);
      qfB[1][j] = (short)f2bf(bf2f((u16)b1[j]) * qs);
    }
  }

  s16x8 ones;
  #pragma unroll
  for (int j = 0; j < 8; j++) ones[j] = (short)0x3F80;  // bf16 1.0

  float mA = -1e30f, mB = -1e30f;
  f32x4 laccA = (f32x4){0.f, 0.f, 0.f, 0.f}, laccB = (f32x4){0.f, 0.f, 0.f, 0.f};
  f32x4 oaccA[4], oaccB[4];
  #pragma unroll
  for (int nt = 0; nt < 4; nt++) {
    oaccA[nt] = (f32x4){0.f, 0.f, 0.f, 0.f};
    oaccB[nt] = (f32x4){0.f, 0.f, 0.f, 0.f};
  }

  // staging: thread t covers rows (t>>3) and (t>>3)+32, 16B segment (t&7),
  // global source pre-swizzled seg^=(row&7), LDS dest linear (rule #21).
  const int seg = tid & 7, sr1 = tid >> 3, sr2 = (tid >> 3) + 32;
  const int ssw1 = (seg ^ (sr1 & 7)) * 8, ssw2 = (seg ^ (sr2 & 7)) * 8;

  const u16* kroot = qkv + ((size_t)b * S + s_base) * 2048 + koff + h * 64;

  auto stage = [&](int kb, int c) {
    const u16* kt = kroot + (size_t)kb * 2048;
    gload16(kt + (size_t)sr1 * 2048 + ssw1, &KT[c][tid * 8]);
    gload16(kt + (size_t)sr2 * 2048 + ssw2, &KT[c][2048 + tid * 8]);
    const u16* vt = vbase + kb;
    gload16(vt + (size_t)sr1 * S + ssw1, &VT[c][tid * 8]);
    gload16(vt + (size_t)sr2 * S + ssw2, &VT[c][2048 + tid * 8]);
  };

  stage(0, 0);
  __syncthreads();

  for (int kb = 0; kb < S_att; kb += 64) {
    const int c = (kb >> 6) & 1;
    if (kb + 64 < S_att) stage(kb + 64, c ^ 1);   // prefetch: drains at end-of-iter barrier

    // K^T Q for both tiles (16 MFMA)
    f32x4 sgA[4], sgB[4];
    __builtin_amdgcn_s_setprio(1);
    #pragma unroll
    for (int g = 0; g < 4; g++) {
      const int key = g * 16 + lr, kw = key & 7;
      const u16* kp = &KT[c][key * 64];
      s16x8 k0 = *reinterpret_cast<const s16x8*>(kp + ((lg ^ kw) * 8));
      s16x8 k1 = *reinterpret_cast<const s16x8*>(kp + (((4 + lg) ^ kw) * 8));
      f32x4 sa = (f32x4){0.f, 0.f, 0.f, 0.f};
      sa = __builtin_amdgcn_mfma_f32_16x16x32_bf16(k0, qfA[0], sa, 0, 0, 0);
      sa = __builtin_amdgcn_mfma_f32_16x16x32_bf16(k1, qfA[1], sa, 0, 0, 0);
      sgA[g] = sa;
      f32x4 sb = (f32x4){0.f, 0.f, 0.f, 0.f};
      sb = __builtin_amdgcn_mfma_f32_16x16x32_bf16(k0, qfB[0], sb, 0, 0, 0);
      sb = __builtin_amdgcn_mfma_f32_16x16x32_bf16(k1, qfB[1], sb, 0, 0, 0);
      sgB[g] = sb;
    }
    __builtin_amdgcn_s_setprio(0);

    // tile maxes: max3-shaped chains (clang fuses fmaxf(fmaxf(a,b),c) -> v_max3_f32)
    float tmA, tmB;
    {
      float m_ = fmaxf(sgA[0][0], sgA[0][1]);
      m_ = fmaxf(fmaxf(m_, sgA[0][2]), sgA[0][3]);
      m_ = fmaxf(fmaxf(m_, sgA[1][0]), sgA[1][1]);
      m_ = fmaxf(fmaxf(m_, sgA[1][2]), sgA[1][3]);
      m_ = fmaxf(fmaxf(m_, sgA[2][0]), sgA[2][1]);
      m_ = fmaxf(fmaxf(m_, sgA[2][2]), sgA[2][3]);
      m_ = fmaxf(fmaxf(m_, sgA[3][0]), sgA[3][1]);
      m_ = fmaxf(fmaxf(m_, sgA[3][2]), sgA[3][3]);
      m_ = fmaxf(m_, __shfl_xor(m_, 16, 64));
      tmA = fmaxf(m_, __shfl_xor(m_, 32, 64));
      float u_ = fmaxf(sgB[0][0], sgB[0][1]);
      u_ = fmaxf(fmaxf(u_, sgB[0][2]), sgB[0][3]);
      u_ = fmaxf(fmaxf(u_, sgB[1][0]), sgB[1][1]);
      u_ = fmaxf(fmaxf(u_, sgB[1][2]), sgB[1][3]);
      u_ = fmaxf(fmaxf(u_, sgB[2][0]), sgB[2][1]);
      u_ = fmaxf(fmaxf(u_, sgB[2][2]), sgB[2][3]);
      u_ = fmaxf(fmaxf(u_, sgB[3][0]), sgB[3][1]);
      u_ = fmaxf(fmaxf(u_, sgB[3][2]), sgB[3][3]);
      u_ = fmaxf(u_, __shfl_xor(u_, 16, 64));
      tmB = fmaxf(u_, __shfl_xor(u_, 32, 64));
    }
    if (__any((int)(tmA > mA + 8.f))) {          // defer-max tile A
      float mnew = fmaxf(mA, tmA);
      float cf = exp2g(mA - mnew);
      mA = mnew;
      #pragma unroll
      for (int r = 0; r < 4; r++) {
        float co = __shfl(cf, lg * 4 + r, 16);
        laccA[r] *= co;
        #pragma unroll
        for (int nt = 0; nt < 4; nt++) oaccA[nt][r] *= co;
      }
    }
    if (__any((int)(tmB > mB + 8.f))) {          // defer-max tile B
      float mnew = fmaxf(mB, tmB);
      float cf = exp2g(mB - mnew);
      mB = mnew;
      #pragma unroll
      for (int r = 0; r < 4; r++) {
        float co = __shfl(cf, lg * 4 + r, 16);
        laccB[r] *= co;
        #pragma unroll
        for (int nt = 0; nt < 4; nt++) oaccB[nt][r] *= co;
      }
    }

    // exp + pack + write BOTH tiles (separate LDS regions), then one drain
    #pragma unroll
    for (int g = 0; g < 4; g++) {
      float e0 = exp2g(sgA[g][0] - mA);
      float e1 = exp2g(sgA[g][1] - mA);
      float e2 = exp2g(sgA[g][2] - mA);
      float e3 = exp2g(sgA[g][3] - mA);
      unsigned p01, p23;
      asm("v_cvt_pk_bf16_f32 %0, %1, %2" : "=v"(p01) : "v"(e0), "v"(e1));
      asm("v_cvt_pk_bf16_f32 %0, %1, %2" : "=v"(p23) : "v"(e2), "v"(e3));
      uint2 pk; pk.x = p01; pk.y = p23;
      *reinterpret_cast<uint2*>(&p_ldsA[lr][g * 16 + lg * 4]) = pk;
    }
    #pragma unroll
    for (int g = 0; g < 4; g++) {
      float e0 = exp2g(sgB[g][0] - mB);
      float e1 = exp2g(sgB[g][1] - mB);
      float e2 = exp2g(sgB[g][2] - mB);
      float e3 = exp2g(sgB[g][3] - mB);
      unsigned p01, p23;
      asm("v_cvt_pk_bf16_f32 %0, %1, %2" : "=v"(p01) : "v"(e0), "v"(e1));
      asm("v_cvt_pk_bf16_f32 %0, %1, %2" : "=v"(p23) : "v"(e2), "v"(e3));
      uint2 pk; pk.x = p01; pk.y = p23;
      *reinterpret_cast<uint2*>(&p_ldsB[lr][g * 16 + lg * 4]) = pk;
    }
    asm volatile("s_waitcnt lgkmcnt(0)" ::: "memory");  // RAW: all P writes visible

    // PV both tiles
    __builtin_amdgcn_s_setprio(1);
    #pragma unroll
    for (int kc = 0; kc < 2; kc++) {
      s16x8 paA = *reinterpret_cast<const s16x8*>(&p_ldsA[lr][kc * 32 + lg * 8]);
      s16x8 paB = *reinterpret_cast<const s16x8*>(&p_ldsB[lr][kc * 32 + lg * 8]);
      laccA = __builtin_amdgcn_mfma_f32_16x16x32_bf16(paA, ones, laccA, 0, 0, 0);
      laccB = __builtin_amdgcn_mfma_f32_16x16x32_bf16(paB, ones, laccB, 0, 0, 0);
      #pragma unroll
      for (int nt = 0; nt < 4; nt++) {
        const int d = nt * 16 + lr;
        s16x8 vfr = *reinterpret_cast<const s16x8*>(
            &VT[c][d * 64 + (((kc * 4 + lg) ^ (d & 7)) * 8)]);
        oaccA[nt] = __builtin_amdgcn_mfma_f32_16x16x32_bf16(paA, vfr, oaccA[nt], 0, 0, 0);
        oaccB[nt] = __builtin_amdgcn_mfma_f32_16x16x32_bf16(paB, vfr, oaccB[nt], 0, 0, 0);
      }
    }
    __builtin_amdgcn_s_setprio(0);

    __syncthreads();  // drains stage vmcnt + all LDS reads; flips buffers safely
  }

  #pragma unroll
  for (int nt = 0; nt < 4; nt++)
    #pragma unroll
    for (int r = 0; r < 4; r++) {
      float vA = oaccA[nt][r] / laccA[r];
      size_t tqA = (size_t)b * S + s_base + q0A + lg * 4 + r;
      ctx[tqA * 1024 + coff + h * 64 + nt * 16 + lr] = f2bf(vA);
      float vB = oaccB[nt][r] / laccB[r];
      size_t tqB = (size_t)b * S + s_base + q0B + lg * 4 + r;
      ctx[tqB * 1024 + coff + h * 64 + nt * 16 + lr] = f2bf(vB);
    }
}

// ---------------- residual add (bf16 branch) + LayerNorm ----------------
template<int NADD>
__global__ void ln_kernel(const float* __restrict__ hin, const u16* __restrict__ a1,
                          const u16* __restrict__ a2, const float* __restrict__ gamma,
                          const float* __restrict__ beta, float* __restrict__ hf,
                          u16* __restrict__ hb) {
  int row = blockIdx.x * 4 + (threadIdx.x >> 6);
  int lane = threadIdx.x & 63;
  size_t base = (size_t)row * 512 + lane * 8;
  float4 h0 = *reinterpret_cast<const float4*>(hin + base);
  float4 h1 = *reinterpret_cast<const float4*>(hin + base + 4);
  s16x8 x1 = *reinterpret_cast<const s16x8*>(a1 + base);
  s16x8 x2 = {};
  if (NADD == 2) x2 = *reinterpret_cast<const s16x8*>(a2 + base);
  float v[8];
  float hv[8] = {h0.x, h0.y, h0.z, h0.w, h1.x, h1.y, h1.z, h1.w};
  float sum = 0.f;
  #pragma unroll
  for (int j = 0; j < 8; j++) {
    float t = hv[j] + bf2f((u16)x1[j]);
    if (NADD == 2) t += bf2f((u16)x2[j]);
    v[j] = t; sum += t;
  }
  #pragma unroll
  for (int o = 32; o >= 1; o >>= 1) sum += __shfl_xor(sum, o, 64);
  float mean = sum * (1.0f / 512.0f);
  float sq = 0.f;
  #pragma unroll
  for (int j = 0; j < 8; j++) { float d = v[j] - mean; sq += d * d; }
  #pragma unroll
  for (int o = 32; o >= 1; o >>= 1) sq += __shfl_xor(sq, o, 64);
  float rstd = rsqrtf(sq * (1.0f / 512.0f) + 1e-5f);
  #pragma unroll
  for (int j = 0; j < 8; j++) {
    int d = lane * 8 + j;
    float o = (v[j] - mean) * rstd * gamma[d] + beta[d];
    hf[base + j] = o;
    hb[base + j] = f2bf(o);
  }
}

// ---------------- final projection (token (s=S-1, b) = b*S + S-1) ----------------
__global__ void out_kernel(const float* __restrict__ hf, const float* __restrict__ Wout,
                           const float* __restrict__ bout, float* __restrict__ out) {
  int b = blockIdx.x; int lane = threadIdx.x;
  size_t base = ((size_t)b * S + S - 1) * 512;
  float s = 0.f;
  #pragma unroll
  for (int j = 0; j < 8; j++) { int d = lane * 8 + j; s += hf[base + d] * Wout[d]; }
  #pragma unroll
  for (int o = 32; o >= 1; o >>= 1) s += __shfl_xor(s, o, 64);
  if (lane == 0) out[b] = s + bout[0];
}

extern "C" void kernel_launch(void* const* d_in, const int* in_sizes, int n_in,
                              void* d_out, int out_size, void* d_ws, size_t ws_size,
                              hipStream_t stream) {
  (void)in_sizes; (void)n_in; (void)out_size; (void)ws_size;
  const float* x      = (const float*)d_in[0];
  const float* W_emb  = (const float*)d_in[1];
  const float* b_emb  = (const float*)d_in[2];
  const float* Wqkv_g = (const float*)d_in[3];
  const float* bqkv_g = (const float*)d_in[4];
  const float* Wo_g   = (const float*)d_in[5];
  const float* bo_g   = (const float*)d_in[6];
  const float* Wqkv_l = (const float*)d_in[7];
  const float* bqkv_l = (const float*)d_in[8];
  const float* Wo_l   = (const float*)d_in[9];
  const float* bo_l   = (const float*)d_in[10];
  const float* W1     = (const float*)d_in[11];
  const float* b1f    = (const float*)d_in[12];
  const float* W2     = (const float*)d_in[13];
  const float* b2f    = (const float*)d_in[14];
  const float* g1     = (const float*)d_in[15];
  const float* be1    = (const float*)d_in[16];
  const float* g2     = (const float*)d_in[17];
  const float* be2    = (const float*)d_in[18];
  const float* W_out  = (const float*)d_in[19];
  const float* b_out  = (const float*)d_in[20];
  float* out = (float*)d_out;

  char* ws = (char*)d_ws;
  u16*   w_bf = (u16*)ws;                       // 32 MiB bf16 weights
  float* h_f  = (float*)(ws + 33554432);        // 32 MiB fp32 master
  u16*   h_b  = (u16*)(ws + 67108864);          // 16 MiB bf16 mirror
  u16*   qkv  = (u16*)(ws + 83886080);          // 64 MiB: [t][2048] = {q_g,k_g,q_l,k_l}
  u16*   ff1  = (u16*)(ws + 83886080);          // aliases qkv (dead by FFN)
  u16*   vpk  = (u16*)(ws + 150994944);         // 32 MiB: v_pk_g | v_pk_l (+8388608 elems)
  u16*   ctx  = (u16*)(ws + 184549376);         // 32 MiB: [t][1024] = ctx_g | ctx_l
  u16*   go   = (u16*)(ws + 218103808);         // 16 MiB bf16 (wo out, also ff2 out) -> 224 MiB

  // fused weight layouts
  u16* wqkvF = w_bf;                 // per layer [3072][512]: rows 0-1535 g, 1536-3071 l
  u16* woF   = w_bf + 6291456;       // per layer [512][1024]: k<512 g, k>=512 l
  u16* w1b   = w_bf + 8388608;
  u16* w2b   = w_bf + 12582912;

  auto cvt = [&](const float* s_, u16* d_, int n) {
    cvt_bf16_kernel<<<(n / 4 + 255) / 256, 256, 0, stream>>>(s_, d_, n / 4);
  };
  for (int i = 0; i < Ln; i++) {
    cvt(Wqkv_g + (size_t)i * 786432, wqkvF + (size_t)i * 1572864, 786432);
    cvt(Wqkv_l + (size_t)i * 786432, wqkvF + (size_t)i * 1572864 + 786432, 786432);
  }
  cvt_wo_kernel<<<2048, 256, 0, stream>>>(Wo_g, Wo_l, woF);
  cvt(W1, w1b, 4194304);
  cvt(W2, w2b, 4194304);

  embed_kernel<<<T, 256, 0, stream>>>(x, W_emb, b_emb, h_f, h_b);

  for (int i = 0; i < Ln; i++) {
    // fused qkv (global+local) with V-transpose epilogue (24x128 = 3072 wgs)
    gemm_bt_kernel<1, 1, 0><<<dim3(3072), 256, 0, stream>>>(
        h_b, wqkvF + (size_t)i * 1572864, bqkv_g + i * 1536, bqkv_l + i * 1536,
        qkv, vpk, T, 3072, 512, 24);
    // merged global+local attention (one launch, 2048 blocks)
    flash_kernel<<<dim3(2048), 256, 0, stream>>>(qkv, vpk, ctx);
    // fused output projection: [ctx_g|ctx_l] @ [Wo_g;Wo_l], bias = bo_g + bo_l (4x128 = 512 wgs)
    gemm_bt_kernel<1, 0, 1><<<dim3(512), 256, 0, stream>>>(
        ctx, woF + (size_t)i * 524288, bo_g + i * 512, bo_l + i * 512,
        go, nullptr, T, 512, 1024, 4);
    // LN1
    ln_kernel<1><<<T / 4, 256, 0, stream>>>(h_f, go, nullptr, g1 + i * 512, be1 + i * 512, h_f, h_b);
    // FFN (16x128 = 2048 wgs; 4x128 = 512 wgs)
    gemm_bt_kernel<2, 0, 0><<<dim3(2048), 256, 0, stream>>>(
        h_b, w1b + (size_t)i * 1048576, b1f + i * 2048, nullptr, ff1, nullptr, T, 2048, 512, 16);
    gemm_bt_kernel<1, 0, 0><<<dim3(512), 256, 0, stream>>>(
        ff1, w2b + (size_t)i * 1048576, b2f + i * 512, nullptr, go, nullptr, T, 512, 2048, 4);
    ln_kernel<1><<<T / 4, 256, 0, stream>>>(h_f, go, nullptr, g2 + i * 512, be2 + i * 512, h_f, h_b);
  }

  out_kernel<<<Bsz, 64, 0, stream>>>(h_f, W_out, b_out, out);
}

// Round 12
// 1373.759 us; speedup vs baseline: 1.2450x; 1.0993x over previous
//
#include <hip/hip_runtime.h>
#include <hip/hip_bf16.h>

#define DEV __device__ __forceinline__

typedef __attribute__((ext_vector_type(4))) float f32x4;
typedef __attribute__((ext_vector_type(8))) short s16x8;
typedef unsigned short u16;

constexpr int Bsz = 8;      // batch
constexpr int S   = 2048;   // sequence
constexpr int Dm  = 512;    // model dim
constexpr int NHd = 8;      // heads
constexpr int FFd = 2048;
constexpr int Ln  = 4;
constexpr int T   = S * Bsz; // 16384 tokens; token index t = b*S + s (batch-major)

DEV u16 f2bf(float f) {
  union { float f; unsigned u; } v; v.f = f;
  unsigned r = v.u + 0x7fff + ((v.u >> 16) & 1);
  return (u16)(r >> 16);
}
DEV float bf2f(u16 a) { union { unsigned u; float f; } v; v.u = ((unsigned)a) << 16; return v.f; }
DEV float exp2g(float x) { return __builtin_amdgcn_exp2f(x); }   // v_exp_f32 (base-2 native)

typedef __attribute__((address_space(1))) const unsigned int guint;
typedef __attribute__((address_space(3))) unsigned int luint;
DEV void gload16(const void* g, void* l) {
  __builtin_amdgcn_global_load_lds((guint*)g, (luint*)l, 16, 0, 0);
}

// ---------------- weight fp32 -> bf16 ----------------
__global__ void cvt_bf16_kernel(const float* __restrict__ src, u16* __restrict__ dst, int n4) {
  int i = (blockIdx.x * 256 + threadIdx.x);
  if (i >= n4) return;
  float4 v = *reinterpret_cast<const float4*>(src + i * 4);
  ushort4 o; o.x = f2bf(v.x); o.y = f2bf(v.y); o.z = f2bf(v.z); o.w = f2bf(v.w);
  *reinterpret_cast<ushort4*>(dst + i * 4) = o;
}

// ---------------- Wo fuse: dst[l][n][k], k<512 from Wo_g, else Wo_l (K-concat) ----------------
__global__ void cvt_wo_kernel(const float* __restrict__ g, const float* __restrict__ l,
                              u16* __restrict__ dst) {
  int i = blockIdx.x * 256 + threadIdx.x;          // over 4-elem groups, total L*512*1024/4
  int e = i * 4;
  int li = e >> 19;
  int rem = e & 524287;
  int n = rem >> 10, k = rem & 1023;
  const float* src = (k < 512) ? (g + ((size_t)li * 512 + n) * 512 + k)
                               : (l + ((size_t)li * 512 + n) * 512 + (k - 512));
  float4 v = *reinterpret_cast<const float4*>(src);
  ushort4 o; o.x = f2bf(v.x); o.y = f2bf(v.y); o.z = f2bf(v.z); o.w = f2bf(v.w);
  *reinterpret_cast<ushort4*>(dst + e) = o;
}

// ---------------- embed + positional encoding (token t = b*S + s) ----------------
__global__ void embed_kernel(const float* __restrict__ x, const float* __restrict__ Wemb,
                             const float* __restrict__ bemb, u16* __restrict__ hb) {
  int t = blockIdx.x;
  int b = t >> 11, s = t & 2047;
  const float* xr = x + ((size_t)b * S + s) * 14;
  float xv[14];
  #pragma unroll
  for (int i = 0; i < 14; i++) xv[i] = xr[i];
  for (int d = threadIdx.x; d < Dm; d += blockDim.x) {
    const float* wr = Wemb + d * 14;
    float acc = bemb[d];
    #pragma unroll
    for (int i = 0; i < 14; i++) acc += xv[i] * wr[i];
    float ang = (float)s * expf((float)((d >> 1) * 2) * (-9.210340371976184f / 512.0f));
    acc += (d & 1) ? cosf(ang) : sinf(ang);
    hb[(size_t)t * Dm + d] = f2bf(acc);
  }
}

// ---------------- GEMM: C(M,N) = A(M,K) @ Bt(N,K)^T + bias ----------------
// 1D grid + T1 XCD-chunked swizzle. OMODE: 1 = bf16 out, 2 = bf16 out + relu.
// VPACK (fused qkv GEMM, N=3072): v-sections scatter transposed into vpk; q/k -> qkv[t][2048].
// BSUM: bias = bias1[col] + bias2[col] (fused wo GEMM).
template<int OMODE, int VPACK, int BSUM>
__global__ __launch_bounds__(256, 3)
void gemm_bt_kernel(const u16* __restrict__ A, const u16* __restrict__ Bt,
                    const float* __restrict__ bias1, const float* __restrict__ bias2,
                    void* __restrict__ Cout, u16* __restrict__ vpk,
                    int M, int N, int K, int nx) {
  __shared__ __align__(16) u16 As[2][128 * 32];
  __shared__ __align__(16) u16 Bs[2][128 * 32];
  const int tid = threadIdx.x;
  const int lane = tid & 63, w = tid >> 6;
  const int wr = w >> 1, wc = w & 1;
  const int lr = lane & 15, lg = lane >> 4;

  // T1: bijective XCD-chunked remap (gridDim.x % 8 == 0)
  const int bid = blockIdx.x;
  const int chunk = gridDim.x >> 3;
  const int swz = (bid & 7) * chunk + (bid >> 3);
  const int n0 = (swz % nx) * 128, m0 = (swz / nx) * 128;

  f32x4 acc[4][4] = {};

  const int c1 = tid, c2 = tid + 256;
  const u16* gA1 = A + (size_t)(m0 + (c1 >> 2)) * K + (c1 & 3) * 8;
  const u16* gA2 = A + (size_t)(m0 + (c2 >> 2)) * K + (c2 & 3) * 8;
  const u16* gB1 = Bt + (size_t)(n0 + (c1 >> 2)) * K + (c1 & 3) * 8;
  const u16* gB2 = Bt + (size_t)(n0 + (c2 >> 2)) * K + (c2 & 3) * 8;

  const int nk = K >> 5;
  auto stage = [&](int t, int c) {
    const int kt = t * 32;
    gload16(gA1 + kt, As[c] + c1 * 8); gload16(gA2 + kt, As[c] + c2 * 8);
    gload16(gB1 + kt, Bs[c] + c1 * 8); gload16(gB2 + kt, Bs[c] + c2 * 8);
  };

  stage(0, 0);
  for (int t = 0; t < nk; ++t) {
    const int c = t & 1;
    if (t + 1 < nk) {
      stage(t + 1, c ^ 1);
      asm volatile("s_waitcnt vmcnt(4)" ::: "memory");
    } else {
      asm volatile("s_waitcnt vmcnt(0)" ::: "memory");
    }
    __builtin_amdgcn_s_barrier();

    s16x8 a[4], bb[4];
    #pragma unroll
    for (int i = 0; i < 4; i++) {
      a[i]  = *reinterpret_cast<const s16x8*>(As[c] + ((wr * 64 + i * 16 + lr) * 32 + lg * 8));
      bb[i] = *reinterpret_cast<const s16x8*>(Bs[c] + ((wc * 64 + i * 16 + lr) * 32 + lg * 8));
    }
    #pragma unroll
    for (int mi = 0; mi < 4; mi++)
      #pragma unroll
      for (int ni = 0; ni < 4; ni++)
        acc[mi][ni] = __builtin_amdgcn_mfma_f32_16x16x32_bf16(a[mi], bb[ni], acc[mi][ni], 0, 0, 0);

    __builtin_amdgcn_s_barrier();
  }

  // epilogue
  const int sec = VPACK ? (n0 >> 9) : 0;            // block-uniform (128 | 512)
  const bool isv = VPACK && (sec == 2 || sec == 5);
  const int ldc = VPACK ? 2048 : N;
  const int csub = (VPACK && sec >= 3) ? 512 : 0;
  u16* vdst = nullptr;
  if (isv) vdst = vpk + (sec == 5 ? 8388608 : 0);

  #pragma unroll
  for (int mi = 0; mi < 4; mi++) {
    int row = m0 + wr * 64 + mi * 16 + lg * 4;
    #pragma unroll
    for (int ni = 0; ni < 4; ni++) {
      int col = n0 + wc * 64 + ni * 16 + lr;
      float bv;
      if (VPACK)      bv = (col < 1536) ? bias1[col] : bias2[col - 1536];
      else if (BSUM)  bv = bias1[col] + bias2[col];
      else            bv = bias1[col];
      if (isv) {
        int vcol = col - (sec == 2 ? 1024 : 2560);
        int hh = vcol >> 6, dd = vcol & 63;
        int bb2 = row >> 11, ss = row & 2047;       // rows = 4 consecutive s within one b
        ushort4 o;
        o.x = f2bf(acc[mi][ni][0] + bv);
        o.y = f2bf(acc[mi][ni][1] + bv);
        o.z = f2bf(acc[mi][ni][2] + bv);
        o.w = f2bf(acc[mi][ni][3] + bv);
        *reinterpret_cast<ushort4*>(vdst + ((size_t)(bb2 * NHd + hh) * 64 + dd) * S + ss) = o;
      } else {
        #pragma unroll
        for (int r = 0; r < 4; r++) {
          float v = acc[mi][ni][r] + bv;
          if (OMODE == 2) v = v > 0.f ? v : 0.f;
          ((u16*)Cout)[(size_t)(row + r) * ldc + (col - csub)] = f2bf(v);
        }
      }
    }
  }
}

// ---------------- flash attention v10: max-free softmax (scores bounded, log2 domain) ----------
// Grid 2048: bid<1024 -> global (S_att=2048), else local (S_att=512). h = bid&7 (XCD pin).
// p = exp2(s) directly (m = 0 fixed): LN'd activations bound |s| << 126, and oacc/lacc is
// scale-invariant, so this is numerically identical to max-subtracted softmax — but removes
// the whole per-iter max tree + shuffles + rescale machinery (~40 VALU ops/iter).
__global__ __launch_bounds__(256, 3)
void flash_kernel(const u16* __restrict__ qkv, const u16* __restrict__ vpk_all,
                  u16* __restrict__ ctx) {
  const int tid = threadIdx.x;
  const int lane = tid & 63, w = tid >> 6;
  const int lr = lane & 15, lg = lane >> 4;
  const int bid = blockIdx.x;
  const int half = bid >> 10;                 // 0 = global, 1 = local
  const int bid10 = bid & 1023;
  const int h = bid10 & 7;
  const int r_ = bid10 >> 3;
  const int S_att = half ? 512 : 2048;
  const int lognqb = half ? 2 : 4;
  const int qb = r_ & ((1 << lognqb) - 1);
  const int cw = r_ >> lognqb;
  const int b = cw & 7, n = cw >> 3;
  const int qoff = half ? 1024 : 0;
  const int koff = half ? 1536 : 512;
  const int coff = half ? 512 : 0;
  const u16* v_pk = vpk_all + (half ? 8388608 : 0);
  const int s_base = n * S_att;
  const int q0A = qb * 128 + w * 16;          // tile A rows
  const int q0B = q0A + 64;                   // tile B rows

  __shared__ __align__(16) u16 KT[2][4096];   // [key 0..63][dk 0..63], seg-swizzled
  __shared__ __align__(16) u16 VT[2][4096];   // [d 0..63][k 0..63],    seg-swizzled
  __shared__ __align__(16) u16 p_lds_all[4][2][16][72];
  u16 (*p_ldsA)[72] = p_lds_all[w][0];
  u16 (*p_ldsB)[72] = p_lds_all[w][1];

  const u16* vbase = v_pk + (size_t)(b * NHd + h) * 64 * S + s_base;

  // Q direct load + scale (0.125 * log2e) + repack to bf16, both tiles
  s16x8 qfA[2], qfB[2];
  {
    const float qs = 0.18033688011112042f;
    const u16* qpA = qkv + ((size_t)b * S + s_base + q0A + lr) * 2048 + qoff + h * 64 + lg * 8;
    const u16* qpB = qkv + ((size_t)b * S + s_base + q0B + lr) * 2048 + qoff + h * 64 + lg * 8;
    s16x8 a0 = *reinterpret_cast<const s16x8*>(qpA);
    s16x8 a1 = *reinterpret_cast<const s16x8*>(qpA + 32);
    s16x8 b0 = *reinterpret_cast<const s16x8*>(qpB);
    s16x8 b1 = *reinterpret_cast<const s16x8*>(qpB + 32);
    #pragma unroll
    for (int j = 0; j < 8; j++) {
      qfA[0][j] = (short)f2bf(bf2f((u16)a0[j]) * qs);
      qfA[1][j] = (short)f2bf(bf2f((u16)a1[j]) * qs);
      qfB[0][j] = (short)f2bf(bf2f((u16)b0[j]) * qs);
      qfB[1][j] = (short)f2bf(bf2f((u16)b1[j]) * qs);
    }
  }

  s16x8 ones;
  #pragma unroll
  for (int j = 0; j < 8; j++) ones[j] = (short)0x3F80;  // bf16 1.0

  f32x4 laccA = (f32x4){0.f, 0.f, 0.f, 0.f}, laccB = (f32x4){0.f, 0.f, 0.f, 0.f};
  f32x4 oaccA[4], oaccB[4];
  #pragma unroll
  for (int nt = 0; nt < 4; nt++) {
    oaccA[nt] = (f32x4){0.f, 0.f, 0.f, 0.f};
    oaccB[nt] = (f32x4){0.f, 0.f, 0.f, 0.f};
  }

  // staging: thread t covers rows (t>>3) and (t>>3)+32, 16B segment (t&7),
  // global source pre-swizzled seg^=(row&7), LDS dest linear (rule #21).
  const int seg = tid & 7, sr1 = tid >> 3, sr2 = (tid >> 3) + 32;
  const int ssw1 = (seg ^ (sr1 & 7)) * 8, ssw2 = (seg ^ (sr2 & 7)) * 8;

  const u16* kroot = qkv + ((size_t)b * S + s_base) * 2048 + koff + h * 64;

  auto stage = [&](int kb, int c) {
    const u16* kt = kroot + (size_t)kb * 2048;
    gload16(kt + (size_t)sr1 * 2048 + ssw1, &KT[c][tid * 8]);
    gload16(kt + (size_t)sr2 * 2048 + ssw2, &KT[c][2048 + tid * 8]);
    const u16* vt = vbase + kb;
    gload16(vt + (size_t)sr1 * S + ssw1, &VT[c][tid * 8]);
    gload16(vt + (size_t)sr2 * S + ssw2, &VT[c][2048 + tid * 8]);
  };

  stage(0, 0);
  __syncthreads();

  for (int kb = 0; kb < S_att; kb += 64) {
    const int c = (kb >> 6) & 1;
    if (kb + 64 < S_att) stage(kb + 64, c ^ 1);   // prefetch: drains at end-of-iter barrier

    // K^T Q for both tiles (16 MFMA)
    f32x4 sgA[4], sgB[4];
    __builtin_amdgcn_s_setprio(1);
    #pragma unroll
    for (int g = 0; g < 4; g++) {
      const int key = g * 16 + lr, kw = key & 7;
      const u16* kp = &KT[c][key * 64];
      s16x8 k0 = *reinterpret_cast<const s16x8*>(kp + ((lg ^ kw) * 8));
      s16x8 k1 = *reinterpret_cast<const s16x8*>(kp + (((4 + lg) ^ kw) * 8));
      f32x4 sa = (f32x4){0.f, 0.f, 0.f, 0.f};
      sa = __builtin_amdgcn_mfma_f32_16x16x32_bf16(k0, qfA[0], sa, 0, 0, 0);
      sa = __builtin_amdgcn_mfma_f32_16x16x32_bf16(k1, qfA[1], sa, 0, 0, 0);
      sgA[g] = sa;
      f32x4 sb = (f32x4){0.f, 0.f, 0.f, 0.f};
      sb = __builtin_amdgcn_mfma_f32_16x16x32_bf16(k0, qfB[0], sb, 0, 0, 0);
      sb = __builtin_amdgcn_mfma_f32_16x16x32_bf16(k1, qfB[1], sb, 0, 0, 0);
      sgB[g] = sb;
    }
    __builtin_amdgcn_s_setprio(0);

    // max-free: p = exp2(s) directly; pack pairs; write both tiles; one drain
    #pragma unroll
    for (int g = 0; g < 4; g++) {
      float e0 = exp2g(sgA[g][0]);
      float e1 = exp2g(sgA[g][1]);
      float e2 = exp2g(sgA[g][2]);
      float e3 = exp2g(sgA[g][3]);
      unsigned p01, p23;
      asm("v_cvt_pk_bf16_f32 %0, %1, %2" : "=v"(p01) : "v"(e0), "v"(e1));
      asm("v_cvt_pk_bf16_f32 %0, %1, %2" : "=v"(p23) : "v"(e2), "v"(e3));
      uint2 pk; pk.x = p01; pk.y = p23;
      *reinterpret_cast<uint2*>(&p_ldsA[lr][g * 16 + lg * 4]) = pk;
    }
    #pragma unroll
    for (int g = 0; g < 4; g++) {
      float e0 = exp2g(sgB[g][0]);
      float e1 = exp2g(sgB[g][1]);
      float e2 = exp2g(sgB[g][2]);
      float e3 = exp2g(sgB[g][3]);
      unsigned p01, p23;
      asm("v_cvt_pk_bf16_f32 %0, %1, %2" : "=v"(p01) : "v"(e0), "v"(e1));
      asm("v_cvt_pk_bf16_f32 %0, %1, %2" : "=v"(p23) : "v"(e2), "v"(e3));
      uint2 pk; pk.x = p01; pk.y = p23;
      *reinterpret_cast<uint2*>(&p_ldsB[lr][g * 16 + lg * 4]) = pk;
    }
    asm volatile("s_waitcnt lgkmcnt(0)" ::: "memory");  // RAW: all P writes visible

    // PV both tiles
    __builtin_amdgcn_s_setprio(1);
    #pragma unroll
    for (int kc = 0; kc < 2; kc++) {
      s16x8 paA = *reinterpret_cast<const s16x8*>(&p_ldsA[lr][kc * 32 + lg * 8]);
      s16x8 paB = *reinterpret_cast<const s16x8*>(&p_ldsB[lr][kc * 32 + lg * 8]);
      laccA = __builtin_amdgcn_mfma_f32_16x16x32_bf16(paA, ones, laccA, 0, 0, 0);
      laccB = __builtin_amdgcn_mfma_f32_16x16x32_bf16(paB, ones, laccB, 0, 0, 0);
      #pragma unroll
      for (int nt = 0; nt < 4; nt++) {
        const int d = nt * 16 + lr;
        s16x8 vfr = *reinterpret_cast<const s16x8*>(
            &VT[c][d * 64 + (((kc * 4 + lg) ^ (d & 7)) * 8)]);
        oaccA[nt] = __builtin_amdgcn_mfma_f32_16x16x32_bf16(paA, vfr, oaccA[nt], 0, 0, 0);
        oaccB[nt] = __builtin_amdgcn_mfma_f32_16x16x32_bf16(paB, vfr, oaccB[nt], 0, 0, 0);
      }
    }
    __builtin_amdgcn_s_setprio(0);

    __syncthreads();  // drains stage vmcnt + all LDS reads; flips buffers safely
  }

  #pragma unroll
  for (int nt = 0; nt < 4; nt++)
    #pragma unroll
    for (int r = 0; r < 4; r++) {
      float vA = oaccA[nt][r] / laccA[r];
      size_t tqA = (size_t)b * S + s_base + q0A + lg * 4 + r;
      ctx[tqA * 1024 + coff + h * 64 + nt * 16 + lr] = f2bf(vA);
      float vB = oaccB[nt][r] / laccB[r];
      size_t tqB = (size_t)b * S + s_base + q0B + lg * 4 + r;
      ctx[tqB * 1024 + coff + h * 64 + nt * 16 + lr] = f2bf(vB);
    }
}

// ---------------- residual add + LayerNorm, bf16 residual stream ----------------
__global__ void ln_kernel(const u16* __restrict__ hin, const u16* __restrict__ a1,
                          const float* __restrict__ gamma, const float* __restrict__ beta,
                          u16* __restrict__ hb) {
  int row = blockIdx.x * 4 + (threadIdx.x >> 6);
  int lane = threadIdx.x & 63;
  size_t base = (size_t)row * 512 + lane * 8;
  s16x8 h0 = *reinterpret_cast<const s16x8*>(hin + base);
  s16x8 x1 = *reinterpret_cast<const s16x8*>(a1 + base);
  float v[8];
  float sum = 0.f;
  #pragma unroll
  for (int j = 0; j < 8; j++) {
    float t = bf2f((u16)h0[j]) + bf2f((u16)x1[j]);
    v[j] = t; sum += t;
  }
  #pragma unroll
  for (int o = 32; o >= 1; o >>= 1) sum += __shfl_xor(sum, o, 64);
  float mean = sum * (1.0f / 512.0f);
  float sq = 0.f;
  #pragma unroll
  for (int j = 0; j < 8; j++) { float d = v[j] - mean; sq += d * d; }
  #pragma unroll
  for (int o = 32; o >= 1; o >>= 1) sq += __shfl_xor(sq, o, 64);
  float rstd = rsqrtf(sq * (1.0f / 512.0f) + 1e-5f);
  s16x8 o8;
  #pragma unroll
  for (int j = 0; j < 8; j++) {
    int d = lane * 8 + j;
    o8[j] = (short)f2bf((v[j] - mean) * rstd * gamma[d] + beta[d]);
  }
  *reinterpret_cast<s16x8*>(hb + base) = o8;
}

// ---------------- final projection (token (s=S-1, b) = b*S + S-1) ----------------
__global__ void out_kernel(const u16* __restrict__ hb, const float* __restrict__ Wout,
                           const float* __restrict__ bout, float* __restrict__ out) {
  int b = blockIdx.x; int lane = threadIdx.x;
  size_t base = ((size_t)b * S + S - 1) * 512;
  float s = 0.f;
  #pragma unroll
  for (int j = 0; j < 8; j++) { int d = lane * 8 + j; s += bf2f(hb[base + d]) * Wout[d]; }
  #pragma unroll
  for (int o = 32; o >= 1; o >>= 1) s += __shfl_xor(s, o, 64);
  if (lane == 0) out[b] = s + bout[0];
}

extern "C" void kernel_launch(void* const* d_in, const int* in_sizes, int n_in,
                              void* d_out, int out_size, void* d_ws, size_t ws_size,
                              hipStream_t stream) {
  (void)in_sizes; (void)n_in; (void)out_size; (void)ws_size;
  const float* x      = (const float*)d_in[0];
  const float* W_emb  = (const float*)d_in[1];
  const float* b_emb  = (const float*)d_in[2];
  const float* Wqkv_g = (const float*)d_in[3];
  const float* bqkv_g = (const float*)d_in[4];
  const float* Wo_g   = (const float*)d_in[5];
  const float* bo_g   = (const float*)d_in[6];
  const float* Wqkv_l = (const float*)d_in[7];
  const float* bqkv_l = (const float*)d_in[8];
  const float* Wo_l   = (const float*)d_in[9];
  const float* bo_l   = (const float*)d_in[10];
  const float* W1     = (const float*)d_in[11];
  const float* b1f    = (const float*)d_in[12];
  const float* W2     = (const float*)d_in[13];
  const float* b2f    = (const float*)d_in[14];
  const float* g1     = (const float*)d_in[15];
  const float* be1    = (const float*)d_in[16];
  const float* g2     = (const float*)d_in[17];
  const float* be2    = (const float*)d_in[18];
  const float* W_out  = (const float*)d_in[19];
  const float* b_out  = (const float*)d_in[20];
  float* out = (float*)d_out;

  char* ws = (char*)d_ws;
  u16*   w_bf = (u16*)ws;                       // 32 MiB bf16 weights
  u16*   h_b  = (u16*)(ws + 67108864);          // 16 MiB bf16 residual stream (master)
  u16*   qkv  = (u16*)(ws + 83886080);          // 64 MiB: [t][2048] = {q_g,k_g,q_l,k_l}
  u16*   ff1  = (u16*)(ws + 83886080);          // aliases qkv (dead by FFN)
  u16*   vpk  = (u16*)(ws + 150994944);         // 32 MiB: v_pk_g | v_pk_l (+8388608 elems)
  u16*   ctx  = (u16*)(ws + 184549376);         // 32 MiB: [t][1024] = ctx_g | ctx_l
  u16*   go   = (u16*)(ws + 218103808);         // 16 MiB bf16 (wo out, also ff2 out) -> 224 MiB

  // fused weight layouts
  u16* wqkvF = w_bf;                 // per layer [3072][512]: rows 0-1535 g, 1536-3071 l
  u16* woF   = w_bf + 6291456;       // per layer [512][1024]: k<512 g, k>=512 l
  u16* w1b   = w_bf + 8388608;
  u16* w2b   = w_bf + 12582912;

  auto cvt = [&](const float* s_, u16* d_, int n) {
    cvt_bf16_kernel<<<(n / 4 + 255) / 256, 256, 0, stream>>>(s_, d_, n / 4);
  };
  for (int i = 0; i < Ln; i++) {
    cvt(Wqkv_g + (size_t)i * 786432, wqkvF + (size_t)i * 1572864, 786432);
    cvt(Wqkv_l + (size_t)i * 786432, wqkvF + (size_t)i * 1572864 + 786432, 786432);
  }
  cvt_wo_kernel<<<2048, 256, 0, stream>>>(Wo_g, Wo_l, woF);
  cvt(W1, w1b, 4194304);
  cvt(W2, w2b, 4194304);

  embed_kernel<<<T, 256, 0, stream>>>(x, W_emb, b_emb, h_b);

  for (int i = 0; i < Ln; i++) {
    // fused qkv (global+local) with V-transpose epilogue (24x128 = 3072 wgs)
    gemm_bt_kernel<1, 1, 0><<<dim3(3072), 256, 0, stream>>>(
        h_b, wqkvF + (size_t)i * 1572864, bqkv_g + i * 1536, bqkv_l + i * 1536,
        qkv, vpk, T, 3072, 512, 24);
    // merged global+local attention (one launch, 2048 blocks)
    flash_kernel<<<dim3(2048), 256, 0, stream>>>(qkv, vpk, ctx);
    // fused output projection: [ctx_g|ctx_l] @ [Wo_g;Wo_l], bias = bo_g + bo_l (4x128 = 512 wgs)
    gemm_bt_kernel<1, 0, 1><<<dim3(512), 256, 0, stream>>>(
        ctx, woF + (size_t)i * 524288, bo_g + i * 512, bo_l + i * 512,
        go, nullptr, T, 512, 1024, 4);
    // LN1 (in-place on h_b)
    ln_kernel<<<T / 4, 256, 0, stream>>>(h_b, go, g1 + i * 512, be1 + i * 512, h_b);
    // FFN (16x128 = 2048 wgs; 4x128 = 512 wgs)
    gemm_bt_kernel<2, 0, 0><<<dim3(2048), 256, 0, stream>>>(
        h_b, w1b + (size_t)i * 1048576, b1f + i * 2048, nullptr, ff1, nullptr, T, 2048, 512, 16);
    gemm_bt_kernel<1, 0, 0><<<dim3(512), 256, 0, stream>>>(
        ff1, w2b + (size_t)i * 1048576, b2f + i * 512, nullptr, go, nullptr, T, 512, 2048, 4);
    ln_kernel<<<T / 4, 256, 0, stream>>>(h_b, go, g2 + i * 512, be2 + i * 512, h_b);
  }

  out_kernel<<<Bsz, 64, 0, stream>>>(h_b, W_out, b_out, out);
}

// Round 13
// 1369.498 us; speedup vs baseline: 1.2489x; 1.0031x over previous
//
#include <hip/hip_runtime.h>
#include <hip/hip_bf16.h>

#define DEV __device__ __forceinline__

typedef __attribute__((ext_vector_type(4))) float f32x4;
typedef __attribute__((ext_vector_type(8))) short s16x8;
typedef unsigned short u16;

constexpr int Bsz = 8;      // batch
constexpr int S   = 2048;   // sequence
constexpr int Dm  = 512;    // model dim
constexpr int NHd = 8;      // heads
constexpr int FFd = 2048;
constexpr int Ln  = 4;
constexpr int T   = S * Bsz; // 16384 tokens; token index t = b*S + s (batch-major)

DEV u16 f2bf(float f) {
  union { float f; unsigned u; } v; v.f = f;
  unsigned r = v.u + 0x7fff + ((v.u >> 16) & 1);
  return (u16)(r >> 16);
}
DEV float bf2f(u16 a) { union { unsigned u; float f; } v; v.u = ((unsigned)a) << 16; return v.f; }
DEV float exp2g(float x) { return __builtin_amdgcn_exp2f(x); }   // v_exp_f32 (base-2 native)

typedef __attribute__((address_space(1))) const unsigned int guint;
typedef __attribute__((address_space(3))) unsigned int luint;
DEV void gload16(const void* g, void* l) {
  __builtin_amdgcn_global_load_lds((guint*)g, (luint*)l, 16, 0, 0);
}

// ---------------- weight fp32 -> bf16 ----------------
__global__ void cvt_bf16_kernel(const float* __restrict__ src, u16* __restrict__ dst, int n4) {
  int i = (blockIdx.x * 256 + threadIdx.x);
  if (i >= n4) return;
  float4 v = *reinterpret_cast<const float4*>(src + i * 4);
  ushort4 o; o.x = f2bf(v.x); o.y = f2bf(v.y); o.z = f2bf(v.z); o.w = f2bf(v.w);
  *reinterpret_cast<ushort4*>(dst + i * 4) = o;
}

// ---------------- Wo fuse: dst[l][n][k], k<512 from Wo_g, else Wo_l (K-concat) ----------------
__global__ void cvt_wo_kernel(const float* __restrict__ g, const float* __restrict__ l,
                              u16* __restrict__ dst) {
  int i = blockIdx.x * 256 + threadIdx.x;          // over 4-elem groups, total L*512*1024/4
  int e = i * 4;
  int li = e >> 19;
  int rem = e & 524287;
  int n = rem >> 10, k = rem & 1023;
  const float* src = (k < 512) ? (g + ((size_t)li * 512 + n) * 512 + k)
                               : (l + ((size_t)li * 512 + n) * 512 + (k - 512));
  float4 v = *reinterpret_cast<const float4*>(src);
  ushort4 o; o.x = f2bf(v.x); o.y = f2bf(v.y); o.z = f2bf(v.z); o.w = f2bf(v.w);
  *reinterpret_cast<ushort4*>(dst + e) = o;
}

// ---------------- embed + positional encoding (token t = b*S + s) ----------------
__global__ void embed_kernel(const float* __restrict__ x, const float* __restrict__ Wemb,
                             const float* __restrict__ bemb, u16* __restrict__ hb) {
  int t = blockIdx.x;
  int b = t >> 11, s = t & 2047;
  const float* xr = x + ((size_t)b * S + s) * 14;
  float xv[14];
  #pragma unroll
  for (int i = 0; i < 14; i++) xv[i] = xr[i];
  for (int d = threadIdx.x; d < Dm; d += blockDim.x) {
    const float* wr = Wemb + d * 14;
    float acc = bemb[d];
    #pragma unroll
    for (int i = 0; i < 14; i++) acc += xv[i] * wr[i];
    float ang = (float)s * expf((float)((d >> 1) * 2) * (-9.210340371976184f / 512.0f));
    acc += (d & 1) ? cosf(ang) : sinf(ang);
    hb[(size_t)t * Dm + d] = f2bf(acc);
  }
}

// ---------------- GEMM: C(M,N) = A(M,K) @ Bt(N,K)^T + bias ----------------
// 1D grid + T1 XCD-chunked swizzle. OMODE: 1 = bf16 out, 2 = bf16 out + relu.
// VPACK (fused qkv GEMM, N=3072): v-sections scatter transposed into vpk; q/k -> qkv[t][2048].
// BSUM: bias = bias1[col] + bias2[col] (fused wo GEMM).
template<int OMODE, int VPACK, int BSUM>
__global__ __launch_bounds__(256, 3)
void gemm_bt_kernel(const u16* __restrict__ A, const u16* __restrict__ Bt,
                    const float* __restrict__ bias1, const float* __restrict__ bias2,
                    void* __restrict__ Cout, u16* __restrict__ vpk,
                    int M, int N, int K, int nx) {
  __shared__ __align__(16) u16 As[2][128 * 32];
  __shared__ __align__(16) u16 Bs[2][128 * 32];
  const int tid = threadIdx.x;
  const int lane = tid & 63, w = tid >> 6;
  const int wr = w >> 1, wc = w & 1;
  const int lr = lane & 15, lg = lane >> 4;

  // T1: bijective XCD-chunked remap (gridDim.x % 8 == 0)
  const int bid = blockIdx.x;
  const int chunk = gridDim.x >> 3;
  const int swz = (bid & 7) * chunk + (bid >> 3);
  const int n0 = (swz % nx) * 128, m0 = (swz / nx) * 128;

  f32x4 acc[4][4] = {};

  const int c1 = tid, c2 = tid + 256;
  const u16* gA1 = A + (size_t)(m0 + (c1 >> 2)) * K + (c1 & 3) * 8;
  const u16* gA2 = A + (size_t)(m0 + (c2 >> 2)) * K + (c2 & 3) * 8;
  const u16* gB1 = Bt + (size_t)(n0 + (c1 >> 2)) * K + (c1 & 3) * 8;
  const u16* gB2 = Bt + (size_t)(n0 + (c2 >> 2)) * K + (c2 & 3) * 8;

  const int nk = K >> 5;
  auto stage = [&](int t, int c) {
    const int kt = t * 32;
    gload16(gA1 + kt, As[c] + c1 * 8); gload16(gA2 + kt, As[c] + c2 * 8);
    gload16(gB1 + kt, Bs[c] + c1 * 8); gload16(gB2 + kt, Bs[c] + c2 * 8);
  };

  stage(0, 0);
  for (int t = 0; t < nk; ++t) {
    const int c = t & 1;
    if (t + 1 < nk) {
      stage(t + 1, c ^ 1);
      asm volatile("s_waitcnt vmcnt(4)" ::: "memory");
    } else {
      asm volatile("s_waitcnt vmcnt(0)" ::: "memory");
    }
    __builtin_amdgcn_s_barrier();

    s16x8 a[4], bb[4];
    #pragma unroll
    for (int i = 0; i < 4; i++) {
      a[i]  = *reinterpret_cast<const s16x8*>(As[c] + ((wr * 64 + i * 16 + lr) * 32 + lg * 8));
      bb[i] = *reinterpret_cast<const s16x8*>(Bs[c] + ((wc * 64 + i * 16 + lr) * 32 + lg * 8));
    }
    #pragma unroll
    for (int mi = 0; mi < 4; mi++)
      #pragma unroll
      for (int ni = 0; ni < 4; ni++)
        acc[mi][ni] = __builtin_amdgcn_mfma_f32_16x16x32_bf16(a[mi], bb[ni], acc[mi][ni], 0, 0, 0);

    __builtin_amdgcn_s_barrier();
  }

  // epilogue
  const int sec = VPACK ? (n0 >> 9) : 0;            // block-uniform (128 | 512)
  const bool isv = VPACK && (sec == 2 || sec == 5);
  const int ldc = VPACK ? 2048 : N;
  const int csub = (VPACK && sec >= 3) ? 512 : 0;
  u16* vdst = nullptr;
  if (isv) vdst = vpk + (sec == 5 ? 8388608 : 0);

  #pragma unroll
  for (int mi = 0; mi < 4; mi++) {
    int row = m0 + wr * 64 + mi * 16 + lg * 4;
    #pragma unroll
    for (int ni = 0; ni < 4; ni++) {
      int col = n0 + wc * 64 + ni * 16 + lr;
      float bv;
      if (VPACK)      bv = (col < 1536) ? bias1[col] : bias2[col - 1536];
      else if (BSUM)  bv = bias1[col] + bias2[col];
      else            bv = bias1[col];
      if (isv) {
        int vcol = col - (sec == 2 ? 1024 : 2560);
        int hh = vcol >> 6, dd = vcol & 63;
        int bb2 = row >> 11, ss = row & 2047;       // rows = 4 consecutive s within one b
        ushort4 o;
        o.x = f2bf(acc[mi][ni][0] + bv);
        o.y = f2bf(acc[mi][ni][1] + bv);
        o.z = f2bf(acc[mi][ni][2] + bv);
        o.w = f2bf(acc[mi][ni][3] + bv);
        *reinterpret_cast<ushort4*>(vdst + ((size_t)(bb2 * NHd + hh) * 64 + dd) * S + ss) = o;
      } else {
        #pragma unroll
        for (int r = 0; r < 4; r++) {
          float v = acc[mi][ni][r] + bv;
          if (OMODE == 2) v = v > 0.f ? v : 0.f;
          ((u16*)Cout)[(size_t)(row + r) * ldc + (col - csub)] = f2bf(v);
        }
      }
    }
  }
}

// ---------------- flash attention v11: counted-vmcnt cross-barrier prefetch (T4) ----------------
// Grid 2048: bid<1024 -> global (S_att=2048), else local (S_att=512). h = bid&7 (XCD pin).
// Per 64-k iter: issue stage(next) -> s_waitcnt vmcnt(8) (current buffer landed; new 8 stay
// in flight ACROSS the barrier) -> raw s_barrier -> QK -> exp2 -> P writes -> lgkmcnt(0)
// -> PV -> raw s_barrier (reads data-consumed; safe WAR for next iter's stage).
// Replaces __syncthreads whose implicit vmcnt(0) drained the prefetch every iteration.
__global__ __launch_bounds__(256, 3)
void flash_kernel(const u16* __restrict__ qkv, const u16* __restrict__ vpk_all,
                  u16* __restrict__ ctx) {
  const int tid = threadIdx.x;
  const int lane = tid & 63, w = tid >> 6;
  const int lr = lane & 15, lg = lane >> 4;
  const int bid = blockIdx.x;
  const int half = bid >> 10;                 // 0 = global, 1 = local
  const int bid10 = bid & 1023;
  const int h = bid10 & 7;
  const int r_ = bid10 >> 3;
  const int S_att = half ? 512 : 2048;
  const int lognqb = half ? 2 : 4;
  const int qb = r_ & ((1 << lognqb) - 1);
  const int cw = r_ >> lognqb;
  const int b = cw & 7, n = cw >> 3;
  const int qoff = half ? 1024 : 0;
  const int koff = half ? 1536 : 512;
  const int coff = half ? 512 : 0;
  const u16* v_pk = vpk_all + (half ? 8388608 : 0);
  const int s_base = n * S_att;
  const int q0A = qb * 128 + w * 16;          // tile A rows
  const int q0B = q0A + 64;                   // tile B rows

  __shared__ __align__(16) u16 KT[2][4096];   // [key 0..63][dk 0..63], seg-swizzled
  __shared__ __align__(16) u16 VT[2][4096];   // [d 0..63][k 0..63],    seg-swizzled
  __shared__ __align__(16) u16 p_lds_all[4][2][16][72];
  u16 (*p_ldsA)[72] = p_lds_all[w][0];
  u16 (*p_ldsB)[72] = p_lds_all[w][1];

  const u16* vbase = v_pk + (size_t)(b * NHd + h) * 64 * S + s_base;

  // Q direct load + scale (0.125 * log2e) + repack to bf16, both tiles
  s16x8 qfA[2], qfB[2];
  {
    const float qs = 0.18033688011112042f;
    const u16* qpA = qkv + ((size_t)b * S + s_base + q0A + lr) * 2048 + qoff + h * 64 + lg * 8;
    const u16* qpB = qkv + ((size_t)b * S + s_base + q0B + lr) * 2048 + qoff + h * 64 + lg * 8;
    s16x8 a0 = *reinterpret_cast<const s16x8*>(qpA);
    s16x8 a1 = *reinterpret_cast<const s16x8*>(qpA + 32);
    s16x8 b0 = *reinterpret_cast<const s16x8*>(qpB);
    s16x8 b1 = *reinterpret_cast<const s16x8*>(qpB + 32);
    #pragma unroll
    for (int j = 0; j < 8; j++) {
      qfA[0][j] = (short)f2bf(bf2f((u16)a0[j]) * qs);
      qfA[1][j] = (short)f2bf(bf2f((u16)a1[j]) * qs);
      qfB[0][j] = (short)f2bf(bf2f((u16)b0[j]) * qs);
      qfB[1][j] = (short)f2bf(bf2f((u16)b1[j]) * qs);
    }
  }

  s16x8 ones;
  #pragma unroll
  for (int j = 0; j < 8; j++) ones[j] = (short)0x3F80;  // bf16 1.0

  f32x4 laccA = (f32x4){0.f, 0.f, 0.f, 0.f}, laccB = (f32x4){0.f, 0.f, 0.f, 0.f};
  f32x4 oaccA[4], oaccB[4];
  #pragma unroll
  for (int nt = 0; nt < 4; nt++) {
    oaccA[nt] = (f32x4){0.f, 0.f, 0.f, 0.f};
    oaccB[nt] = (f32x4){0.f, 0.f, 0.f, 0.f};
  }

  // staging: thread t covers rows (t>>3) and (t>>3)+32, 16B segment (t&7),
  // global source pre-swizzled seg^=(row&7), LDS dest linear (rule #21).
  const int seg = tid & 7, sr1 = tid >> 3, sr2 = (tid >> 3) + 32;
  const int ssw1 = (seg ^ (sr1 & 7)) * 8, ssw2 = (seg ^ (sr2 & 7)) * 8;

  const u16* kroot = qkv + ((size_t)b * S + s_base) * 2048 + koff + h * 64;

  auto stage = [&](int kb, int c) {
    const u16* kt = kroot + (size_t)kb * 2048;
    gload16(kt + (size_t)sr1 * 2048 + ssw1, &KT[c][tid * 8]);
    gload16(kt + (size_t)sr2 * 2048 + ssw2, &KT[c][2048 + tid * 8]);
    const u16* vt = vbase + kb;
    gload16(vt + (size_t)sr1 * S + ssw1, &VT[c][tid * 8]);
    gload16(vt + (size_t)sr2 * S + ssw2, &VT[c][2048 + tid * 8]);
  };

  stage(0, 0);   // no barrier here: first-iter top barrier covers it

  for (int kb = 0; kb < S_att; kb += 64) {
    const int c = (kb >> 6) & 1;
    if (kb + 64 < S_att) {
      stage(kb + 64, c ^ 1);                           // 8 new loads -> stay in flight
      asm volatile("s_waitcnt vmcnt(8)" ::: "memory"); // my 8 loads for buffer c landed
    } else {
      asm volatile("s_waitcnt vmcnt(0)" ::: "memory");
    }
    asm volatile("s_barrier" ::: "memory");            // all waves' buffer c ready (RAW+WAR)

    // K^T Q for both tiles (16 MFMA)
    f32x4 sgA[4], sgB[4];
    __builtin_amdgcn_s_setprio(1);
    #pragma unroll
    for (int g = 0; g < 4; g++) {
      const int key = g * 16 + lr, kw = key & 7;
      const u16* kp = &KT[c][key * 64];
      s16x8 k0 = *reinterpret_cast<const s16x8*>(kp + ((lg ^ kw) * 8));
      s16x8 k1 = *reinterpret_cast<const s16x8*>(kp + (((4 + lg) ^ kw) * 8));
      f32x4 sa = (f32x4){0.f, 0.f, 0.f, 0.f};
      sa = __builtin_amdgcn_mfma_f32_16x16x32_bf16(k0, qfA[0], sa, 0, 0, 0);
      sa = __builtin_amdgcn_mfma_f32_16x16x32_bf16(k1, qfA[1], sa, 0, 0, 0);
      sgA[g] = sa;
      f32x4 sb = (f32x4){0.f, 0.f, 0.f, 0.f};
      sb = __builtin_amdgcn_mfma_f32_16x16x32_bf16(k0, qfB[0], sb, 0, 0, 0);
      sb = __builtin_amdgcn_mfma_f32_16x16x32_bf16(k1, qfB[1], sb, 0, 0, 0);
      sgB[g] = sb;
    }
    __builtin_amdgcn_s_setprio(0);

    // max-free: p = exp2(s) directly; pack pairs; write both tiles; one drain
    #pragma unroll
    for (int g = 0; g < 4; g++) {
      float e0 = exp2g(sgA[g][0]);
      float e1 = exp2g(sgA[g][1]);
      float e2 = exp2g(sgA[g][2]);
      float e3 = exp2g(sgA[g][3]);
      unsigned p01, p23;
      asm("v_cvt_pk_bf16_f32 %0, %1, %2" : "=v"(p01) : "v"(e0), "v"(e1));
      asm("v_cvt_pk_bf16_f32 %0, %1, %2" : "=v"(p23) : "v"(e2), "v"(e3));
      uint2 pk; pk.x = p01; pk.y = p23;
      *reinterpret_cast<uint2*>(&p_ldsA[lr][g * 16 + lg * 4]) = pk;
    }
    #pragma unroll
    for (int g = 0; g < 4; g++) {
      float e0 = exp2g(sgB[g][0]);
      float e1 = exp2g(sgB[g][1]);
      float e2 = exp2g(sgB[g][2]);
      float e3 = exp2g(sgB[g][3]);
      unsigned p01, p23;
      asm("v_cvt_pk_bf16_f32 %0, %1, %2" : "=v"(p01) : "v"(e0), "v"(e1));
      asm("v_cvt_pk_bf16_f32 %0, %1, %2" : "=v"(p23) : "v"(e2), "v"(e3));
      uint2 pk; pk.x = p01; pk.y = p23;
      *reinterpret_cast<uint2*>(&p_ldsB[lr][g * 16 + lg * 4]) = pk;
    }
    asm volatile("s_waitcnt lgkmcnt(0)" ::: "memory");  // RAW: all P writes visible

    // PV both tiles
    __builtin_amdgcn_s_setprio(1);
    #pragma unroll
    for (int kc = 0; kc < 2; kc++) {
      s16x8 paA = *reinterpret_cast<const s16x8*>(&p_ldsA[lr][kc * 32 + lg * 8]);
      s16x8 paB = *reinterpret_cast<const s16x8*>(&p_ldsB[lr][kc * 32 + lg * 8]);
      laccA = __builtin_amdgcn_mfma_f32_16x16x32_bf16(paA, ones, laccA, 0, 0, 0);
      laccB = __builtin_amdgcn_mfma_f32_16x16x32_bf16(paB, ones, laccB, 0, 0, 0);
      #pragma unroll
      for (int nt = 0; nt < 4; nt++) {
        const int d = nt * 16 + lr;
        s16x8 vfr = *reinterpret_cast<const s16x8*>(
            &VT[c][d * 64 + (((kc * 4 + lg) ^ (d & 7)) * 8)]);
        oaccA[nt] = __builtin_amdgcn_mfma_f32_16x16x32_bf16(paA, vfr, oaccA[nt], 0, 0, 0);
        oaccB[nt] = __builtin_amdgcn_mfma_f32_16x16x32_bf16(paB, vfr, oaccB[nt], 0, 0, 0);
      }
    }
    __builtin_amdgcn_s_setprio(0);

    // WAR fence only: all LDS reads were data-consumed by MFMAs above (compiler-inserted
    // lgkmcnt), so a raw barrier suffices — prefetch stays in flight across it.
    asm volatile("s_barrier" ::: "memory");
  }

  #pragma unroll
  for (int nt = 0; nt < 4; nt++)
    #pragma unroll
    for (int r = 0; r < 4; r++) {
      float vA = oaccA[nt][r] / laccA[r];
      size_t tqA = (size_t)b * S + s_base + q0A + lg * 4 + r;
      ctx[tqA * 1024 + coff + h * 64 + nt * 16 + lr] = f2bf(vA);
      float vB = oaccB[nt][r] / laccB[r];
      size_t tqB = (size_t)b * S + s_base + q0B + lg * 4 + r;
      ctx[tqB * 1024 + coff + h * 64 + nt * 16 + lr] = f2bf(vB);
    }
}

// ---------------- residual add + LayerNorm, bf16 residual stream ----------------
__global__ void ln_kernel(const u16* __restrict__ hin, const u16* __restrict__ a1,
                          const float* __restrict__ gamma, const float* __restrict__ beta,
                          u16* __restrict__ hb) {
  int row = blockIdx.x * 4 + (threadIdx.x >> 6);
  int lane = threadIdx.x & 63;
  size_t base = (size_t)row * 512 + lane * 8;
  s16x8 h0 = *reinterpret_cast<const s16x8*>(hin + base);
  s16x8 x1 = *reinterpret_cast<const s16x8*>(a1 + base);
  float v[8];
  float sum = 0.f;
  #pragma unroll
  for (int j = 0; j < 8; j++) {
    float t = bf2f((u16)h0[j]) + bf2f((u16)x1[j]);
    v[j] = t; sum += t;
  }
  #pragma unroll
  for (int o = 32; o >= 1; o >>= 1) sum += __shfl_xor(sum, o, 64);
  float mean = sum * (1.0f / 512.0f);
  float sq = 0.f;
  #pragma unroll
  for (int j = 0; j < 8; j++) { float d = v[j] - mean; sq += d * d; }
  #pragma unroll
  for (int o = 32; o >= 1; o >>= 1) sq += __shfl_xor(sq, o, 64);
  float rstd = rsqrtf(sq * (1.0f / 512.0f) + 1e-5f);
  s16x8 o8;
  #pragma unroll
  for (int j = 0; j < 8; j++) {
    int d = lane * 8 + j;
    o8[j] = (short)f2bf((v[j] - mean) * rstd * gamma[d] + beta[d]);
  }
  *reinterpret_cast<s16x8*>(hb + base) = o8;
}

// ---------------- final projection (token (s=S-1, b) = b*S + S-1) ----------------
__global__ void out_kernel(const u16* __restrict__ hb, const float* __restrict__ Wout,
                           const float* __restrict__ bout, float* __restrict__ out) {
  int b = blockIdx.x; int lane = threadIdx.x;
  size_t base = ((size_t)b * S + S - 1) * 512;
  float s = 0.f;
  #pragma unroll
  for (int j = 0; j < 8; j++) { int d = lane * 8 + j; s += bf2f(hb[base + d]) * Wout[d]; }
  #pragma unroll
  for (int o = 32; o >= 1; o >>= 1) s += __shfl_xor(s, o, 64);
  if (lane == 0) out[b] = s + bout[0];
}

extern "C" void kernel_launch(void* const* d_in, const int* in_sizes, int n_in,
                              void* d_out, int out_size, void* d_ws, size_t ws_size,
                              hipStream_t stream) {
  (void)in_sizes; (void)n_in; (void)out_size; (void)ws_size;
  const float* x      = (const float*)d_in[0];
  const float* W_emb  = (const float*)d_in[1];
  const float* b_emb  = (const float*)d_in[2];
  const float* Wqkv_g = (const float*)d_in[3];
  const float* bqkv_g = (const float*)d_in[4];
  const float* Wo_g   = (const float*)d_in[5];
  const float* bo_g   = (const float*)d_in[6];
  const float* Wqkv_l = (const float*)d_in[7];
  const float* bqkv_l = (const float*)d_in[8];
  const float* Wo_l   = (const float*)d_in[9];
  const float* bo_l   = (const float*)d_in[10];
  const float* W1     = (const float*)d_in[11];
  const float* b1f    = (const float*)d_in[12];
  const float* W2     = (const float*)d_in[13];
  const float* b2f    = (const float*)d_in[14];
  const float* g1     = (const float*)d_in[15];
  const float* be1    = (const float*)d_in[16];
  const float* g2     = (const float*)d_in[17];
  const float* be2    = (const float*)d_in[18];
  const float* W_out  = (const float*)d_in[19];
  const float* b_out  = (const float*)d_in[20];
  float* out = (float*)d_out;

  char* ws = (char*)d_ws;
  u16*   w_bf = (u16*)ws;                       // 32 MiB bf16 weights
  u16*   h_b  = (u16*)(ws + 67108864);          // 16 MiB bf16 residual stream (master)
  u16*   qkv  = (u16*)(ws + 83886080);          // 64 MiB: [t][2048] = {q_g,k_g,q_l,k_l}
  u16*   ff1  = (u16*)(ws + 83886080);          // aliases qkv (dead by FFN)
  u16*   vpk  = (u16*)(ws + 150994944);         // 32 MiB: v_pk_g | v_pk_l (+8388608 elems)
  u16*   ctx  = (u16*)(ws + 184549376);         // 32 MiB: [t][1024] = ctx_g | ctx_l
  u16*   go   = (u16*)(ws + 218103808);         // 16 MiB bf16 (wo out, also ff2 out) -> 224 MiB

  // fused weight layouts
  u16* wqkvF = w_bf;                 // per layer [3072][512]: rows 0-1535 g, 1536-3071 l
  u16* woF   = w_bf + 6291456;       // per layer [512][1024]: k<512 g, k>=512 l
  u16* w1b   = w_bf + 8388608;
  u16* w2b   = w_bf + 12582912;

  auto cvt = [&](const float* s_, u16* d_, int n) {
    cvt_bf16_kernel<<<(n / 4 + 255) / 256, 256, 0, stream>>>(s_, d_, n / 4);
  };
  for (int i = 0; i < Ln; i++) {
    cvt(Wqkv_g + (size_t)i * 786432, wqkvF + (size_t)i * 1572864, 786432);
    cvt(Wqkv_l + (size_t)i * 786432, wqkvF + (size_t)i * 1572864 + 786432, 786432);
  }
  cvt_wo_kernel<<<2048, 256, 0, stream>>>(Wo_g, Wo_l, woF);
  cvt(W1, w1b, 4194304);
  cvt(W2, w2b, 4194304);

  embed_kernel<<<T, 256, 0, stream>>>(x, W_emb, b_emb, h_b);

  for (int i = 0; i < Ln; i++) {
    // fused qkv (global+local) with V-transpose epilogue (24x128 = 3072 wgs)
    gemm_bt_kernel<1, 1, 0><<<dim3(3072), 256, 0, stream>>>(
        h_b, wqkvF + (size_t)i * 1572864, bqkv_g + i * 1536, bqkv_l + i * 1536,
        qkv, vpk, T, 3072, 512, 24);
    // merged global+local attention (one launch, 2048 blocks)
    flash_kernel<<<dim3(2048), 256, 0, stream>>>(qkv, vpk, ctx);
    // fused output projection: [ctx_g|ctx_l] @ [Wo_g;Wo_l], bias = bo_g + bo_l (4x128 = 512 wgs)
    gemm_bt_kernel<1, 0, 1><<<dim3(512), 256, 0, stream>>>(
        ctx, woF + (size_t)i * 524288, bo_g + i * 512, bo_l + i * 512,
        go, nullptr, T, 512, 1024, 4);
    // LN1 (in-place on h_b)
    ln_kernel<<<T / 4, 256, 0, stream>>>(h_b, go, g1 + i * 512, be1 + i * 512, h_b);
    // FFN (16x128 = 2048 wgs; 4x128 = 512 wgs)
    gemm_bt_kernel<2, 0, 0><<<dim3(2048), 256, 0, stream>>>(
        h_b, w1b + (size_t)i * 1048576, b1f + i * 2048, nullptr, ff1, nullptr, T, 2048, 512, 16);
    gemm_bt_kernel<1, 0, 0><<<dim3(512), 256, 0, stream>>>(
        ff1, w2b + (size_t)i * 1048576, b2f + i * 512, nullptr, go, nullptr, T, 512, 2048, 4);
    ln_kernel<<<T / 4, 256, 0, stream>>>(h_b, go, g2 + i * 512, be2 + i * 512, h_b);
  }

  out_kernel<<<Bsz, 64, 0, stream>>>(h_b, W_out, b_out, out);
}